// Round 3
// baseline (1335.638 us; speedup 1.0000x reference)
//
#include <hip/hip_runtime.h>

// ---------------------------------------------------------------------------
// Round 18: SPLIT KERNEL experiment. r16 (store rebalance) null + r17 (nt
// stores) partial -> theory: 5 interleaved per-block write streams in
// barrier-synced bursts lose HBM row locality as 256 blocks drift (~3.9 TB/s
// effective vs 6.5 fill). Split:
//   kernel1 lstm_rec: recurrence only (8 gate waves), writes h/c only.
//   kernel2 heads_kernel: 6400 independent (t, 32-batch) tiles; reads fp32 h
//   back (lossless bf16 round-trip -> absmax unchanged), computes bo/pc/hd
//   with fused weights, LDS-coalesced contiguous 32KB slab stores, block
//   order = memory order -> sequential global sweep per region (fill-like).
// prep unchanged. All output stores non-temporal.
// MFMA 16x16x32 bf16 (m89): A: row=l&15,k=8*(l>>4)+j; B: col=l&15 (batch);
// C/D: col=l&15 (batch), row=4*(l>>4)+j (feature).
// ---------------------------------------------------------------------------

typedef __bf16 bf16_t;
typedef __bf16 bf16x4 __attribute__((ext_vector_type(4)));
typedef __bf16 bf16x8 __attribute__((ext_vector_type(8)));
typedef float  f32x4  __attribute__((ext_vector_type(4)));

static_assert(sizeof(bf16x8) == 16, "bf16x8 must be 16B");

#define MFMA16(a, b, c) __builtin_amdgcn_mfma_f32_16x16x32_bf16((a), (b), (c), 0, 0, 0)

constexpr int TT = 100, BB = 2048;
constexpr long O_HD = 0;
constexpr long O_PC = O_HD + (long)TT * BB * 12;    // 2,457,600
constexpr long O_BO = O_PC + (long)TT * BB * 256;   // 54,886,400
constexpr long O_H  = O_BO + (long)TT * BB * 256;   // 107,315,200
constexpr long O_C  = O_H  + (long)TT * BB * 128;   // 133,529,600

// d_ws bf16 frag layout (A-operand order: entry = M[k][out_feature]):
constexpr int WS_U   = 0;        // 32 tiles x 5 s x 512 = 81920 (k128-130=W, k131=b)
constexpr int WS_WB  = 81920;    // 16 tiles x 4 s x 512 = 32768
constexpr int WS_WPF = 114688;   // fused Wb@Wpc: 16 tiles x 4 s x 512 = 32768
constexpr int WS_WHF = 147456;   // fused Wb@Whd: 1 tile x 4 s x 512 = 2048

__device__ __forceinline__ float fast_sigmoid(float x) {
  return __builtin_amdgcn_rcpf(1.0f + __builtin_amdgcn_exp2f(-1.442695040888963f * x));
}
__device__ __forceinline__ float fast_tanh(float x) {
  float e = __builtin_amdgcn_exp2f(2.885390081777927f * x);  // exp(2x)
  return 1.0f - 2.0f * __builtin_amdgcn_rcpf(e + 1.0f);
}

__device__ __forceinline__ void nt_store4(float* p, f32x4 v) {
  __builtin_nontemporal_store(v, (f32x4*)p);
}

// ---------------------------------------------------------------------------
// prep v2 (unchanged): blocks 0-39 U-aug repack; 40-55 Wb repack; 56-119
// Wb@Wpc fusion; 120-123 Wb@Whd fusion.
// ---------------------------------------------------------------------------
__global__ void prep_kernel(const float* __restrict__ U, const float* __restrict__ W,
                            const float* __restrict__ b_, const float* __restrict__ Wb,
                            const float* __restrict__ Wpc, const float* __restrict__ Whd,
                            bf16_t* __restrict__ ws) {
  const int blk = blockIdx.x, tid = threadIdx.x;
  if (blk < 40) {                        // U augmented: 32 tiles x 5 K-slices
    int g = blk * 256 + tid;
    int tile = g / 320, rem = g % 320, s = rem >> 6, l = rem & 63;
    int cl = l & 15, kg = l >> 4, fb = tile * 16;
    bf16x8 v;
#pragma unroll
    for (int j = 0; j < 8; j++) {
      int k = 32 * s + 8 * kg + j;
      float e = 0.0f;
      if (k < 128) e = U[(size_t)k * 512 + fb + cl];
      else if (k < 131) e = W[(size_t)(k - 128) * 512 + fb + cl];
      else if (k == 131) e = b_[fb + cl];
      v[j] = (bf16_t)e;
    }
    *(bf16x8*)(ws + WS_U + (size_t)g * 8) = v;
  } else if (blk < 56) {                 // Wb^T frags: 16 tiles x 4 s
    int gg = (blk - 40) * 256 + tid;
    int tile = gg >> 8, s = (gg >> 6) & 3, l = gg & 63;
    int cl = l & 15, kg = l >> 4;
    bf16x8 v;
#pragma unroll
    for (int j = 0; j < 8; j++)
      v[j] = (bf16_t)Wb[(size_t)(32 * s + 8 * kg + j) * 256 + tile * 16 + cl];
    *(bf16x8*)(ws + WS_WB + (size_t)gg * 8) = v;
  } else if (blk < 120) {                // fused (Wb@Wpc)^T: one (tile,s)/block
    __shared__ float wpcol[256][17];
    int c = blk - 56, tile = c >> 2, s = c & 3;
    for (int i = tid; i < 4096; i += 256)
      wpcol[i >> 4][i & 15] = Wpc[(size_t)(i >> 4) * 256 + tile * 16 + (i & 15)];
    __syncthreads();
    int l = tid & 63, jp = tid >> 6;     // jp in 0..3 -> j = 2jp, 2jp+1
    int cl = l & 15, kg = l >> 4;
    const float* wb0 = Wb + (size_t)(32 * s + 8 * kg + 2 * jp) * 256;
    const float* wb1 = wb0 + 256;
    float d0 = 0.f, d1 = 0.f;
#pragma unroll 8
    for (int n = 0; n < 256; n++) {
      float wv = wpcol[n][cl];
      d0 += wb0[n] * wv;
      d1 += wb1[n] * wv;
    }
    bf16_t* dst = ws + WS_WPF + ((size_t)(tile * 4 + s) * 64 + l) * 8 + 2 * jp;
    dst[0] = (bf16_t)d0;
    dst[1] = (bf16_t)d1;
  } else {                               // fused (Wb@Whd)^T: one s/block (4)
    __shared__ float wpcol[256][17];
    int s = blk - 120;
    for (int i = tid; i < 4096; i += 256) {
      int n = i >> 4, p = i & 15;
      wpcol[n][p] = (p < 12) ? Whd[(size_t)n * 12 + p] : 0.0f;
    }
    __syncthreads();
    int l = tid & 63, jp = tid >> 6;
    int cl = l & 15, kg = l >> 4;
    const float* wb0 = Wb + (size_t)(32 * s + 8 * kg + 2 * jp) * 256;
    const float* wb1 = wb0 + 256;
    float d0 = 0.f, d1 = 0.f;
#pragma unroll 8
    for (int n = 0; n < 256; n++) {
      float wv = wpcol[n][cl];
      d0 += wb0[n] * wv;
      d1 += wb1[n] * wv;
    }
    bf16_t* dst = ws + WS_WHF + ((size_t)s * 64 + l) * 8 + 2 * jp;
    dst[0] = (bf16_t)d0;
    dst[1] = (bf16_t)d1;
  }
}

// ---------------------------------------------------------------------------
// kernel1: recurrence only. 256 blocks x 512 threads (8 gate waves).
// Writes h (fp32, from bf16 values) and c (fp32) only.
// ---------------------------------------------------------------------------
__global__ __launch_bounds__(512, 2) void lstm_rec(
    const float* __restrict__ x, const float* __restrict__ ini,
    const float* __restrict__ Wh, const float* __restrict__ bh,
    const float* __restrict__ Wc, const float* __restrict__ bc,
    const bf16_t* __restrict__ ws, float* __restrict__ out) {
  __shared__ bf16_t hl[2][16][168];     // h(0:128)|x(128:131)|0; rows 8-15 zero
  __shared__ bf16_t xbl[TT][8][4];      // {x0,x1,x2,1.0} per (t,row), 6.25 KB
  __shared__ float  il[8][268];
  __shared__ float  cstg[2][8][132];    // fp32 c staging (dbuf), 8.25 KB

  const int tid = threadIdx.x;
  const int w   = tid >> 6;             // 0..7
  const int l   = tid & 63;
  const int cl  = l & 15;
  const int kg  = l >> 4;
  const int gb0 = blockIdx.x * 8;

  // ---- cooperative LDS init ----
  for (int i = tid; i < 2 * 16 * 168; i += 512) ((bf16_t*)hl)[i] = (bf16_t)0.f;
  for (int i = tid; i < TT * 8; i += 512) {
    int t = i >> 3, r = i & 7;
    const float* xp = x + ((size_t)t * BB + gb0 + r) * 3;
    bf16x4 v = {(bf16_t)xp[0], (bf16_t)xp[1], (bf16_t)xp[2], (bf16_t)1.0f};
    *(bf16x4*)&xbl[t][r][0] = v;
  }
  for (int i = tid; i < 8 * 268; i += 512) {
    int r = i / 268, k = i - r * 268;
    il[r][k] = ini[(size_t)(gb0 + r) * 268 + k];
  }
  __syncthreads();

  const int fb4 = w * 16 + 4 * kg;      // 4 consecutive h-features owned

  // h/c store assignment: even wave -> h quarter, odd wave -> c quarter
  const int q    = w >> 1;              // quarter 0..3
  const int sf   = q * 256 + l * 4;     // flat float index in 8x128 region
  const int srow = sf >> 7;             // 2q or 2q+1
  const int scol = sf & 127;
  float* sptr = out + ((w & 1) ? O_C : O_H) + (size_t)gb0 * 128 + sf;  // tm=0

  bf16x8 uf[4][5];
#pragma unroll
  for (int n = 0; n < 4; n++)
#pragma unroll
    for (int s = 0; s < 5; s++)
      uf[n][s] = *(const bf16x8*)(ws + WS_U + (size_t)((n * 8 + w) * 5 + s) * 512 + l * 8);

  // ---- h0/c0 = init @ Wh/Wc + bh/bc ----
  f32x4 cst;
  {
    f32x4 ha = *(const f32x4*)&bh[fb4];
    f32x4 ca = *(const f32x4*)&bc[fb4];
    for (int k = 0; k < 268; k++) {
      float iv = il[cl & 7][k];
      ha += iv * *(const f32x4*)&Wh[(size_t)k * 128 + fb4];
      ca += iv * *(const f32x4*)&Wc[(size_t)k * 128 + fb4];
    }
    cst = ca;
    if (cl < 8) {
      bf16x4 hv = {(bf16_t)ha[0], (bf16_t)ha[1], (bf16_t)ha[2], (bf16_t)ha[3]};
      *(bf16x4*)&hl[0][cl][fb4] = hv;
    }
  }
  if (tid < 8) *(bf16x4*)&hl[0][tid][128] = *(const bf16x4*)&xbl[0][tid][0];
  asm volatile("s_waitcnt lgkmcnt(0)" ::: "memory");
  __builtin_amdgcn_s_barrier();

  for (int t = 0; t <= TT; t++) {
    // ---- store h(t-1) or c(t-1): one 1KB burst per wave ----
    if (t >= 1) {
      int tm = t - 1;
      if (w & 1) {
        f32x4 vc = *(const f32x4*)&cstg[tm & 1][srow][scol];
        nt_store4(sptr, vc);
      } else {
        // h(t-1) lives in hl[t&1] (bf16); lossless fp32 round trip
        bf16x4 hb = *(const bf16x4*)&hl[t & 1][srow][scol];
        f32x4 vh = {(float)hb[0], (float)hb[1], (float)hb[2], (float)hb[3]};
        nt_store4(sptr, vh);
      }
      sptr += (size_t)BB * 128;
    }
    if (t < TT) {
      bf16x8 hfrag[5];
#pragma unroll
      for (int s = 0; s < 5; s++) hfrag[s] = *(const bf16x8*)&hl[t & 1][cl][32 * s + 8 * kg];

      // split accumulator chains: depth 3 + depth 2, then add
      f32x4 acc[4], acc2[4];
#pragma unroll
      for (int n = 0; n < 4; n++) {
        acc[n]  = (f32x4){0.f, 0.f, 0.f, 0.f};
        acc2[n] = (f32x4){0.f, 0.f, 0.f, 0.f};
      }
#pragma unroll
      for (int s = 0; s < 3; s++)
#pragma unroll
        for (int n = 0; n < 4; n++) acc[n] = MFMA16(uf[n][s], hfrag[s], acc[n]);
#pragma unroll
      for (int s = 3; s < 5; s++)
#pragma unroll
        for (int n = 0; n < 4; n++) acc2[n] = MFMA16(uf[n][s], hfrag[s], acc2[n]);
#pragma unroll
      for (int n = 0; n < 4; n++) acc[n] += acc2[n];

      f32x4 hv4;
#pragma unroll
      for (int j = 0; j < 4; j++) {
        float iv = fast_sigmoid(acc[0][j]);
        float fv = fast_sigmoid(acc[1][j]);
        float gv = fast_tanh(acc[2][j]);
        float ov = fast_sigmoid(acc[3][j]);
        float cv = fv * cst[j] + iv * gv;
        cst[j] = cv;
        hv4[j] = ov * fast_tanh(cv);
      }
      if (cl < 8) {
        bf16x4 hb = {(bf16_t)hv4[0], (bf16_t)hv4[1], (bf16_t)hv4[2], (bf16_t)hv4[3]};
        *(bf16x4*)&hl[(t + 1) & 1][cl][fb4] = hb;
        *(f32x4*)&cstg[t & 1][cl][fb4] = cst;
      }
      if (tid < 8 && t + 1 < TT)
        *(bf16x4*)&hl[(t + 1) & 1][tid][128] = *(const bf16x4*)&xbl[t + 1][tid][0];
    }
    asm volatile("s_waitcnt lgkmcnt(0)" ::: "memory");
    __builtin_amdgcn_s_barrier();
    __builtin_amdgcn_sched_barrier(0);
  }
}

// ---------------------------------------------------------------------------
// kernel2: heads. One block per (t, 32-batch-row) tile: 100*64 = 6400 blocks
// x 256 threads (4 waves). Reads fp32 h, computes bo/pc/hd via fused weights
// (read per-MFMA from ws, L2-hot), stores LDS-coalesced contiguous slabs.
// blockIdx = t*64 + bc -> in-flight blocks sweep memory sequentially.
// ---------------------------------------------------------------------------
__global__ __launch_bounds__(256, 3) void heads_kernel(
    const float* __restrict__ bpc, const float* __restrict__ bhd,
    const bf16_t* __restrict__ ws, float* __restrict__ out) {
  __shared__ float stg[32][260];        // 33.3 KB bo/pc staging
  __shared__ float hdst[392];           // 32x12 hd staging + pad

  const int idx = blockIdx.x;
  const int t   = idx >> 6;
  const int b0  = (idx & 63) * 32;
  const int tid = threadIdx.x;
  const int hw  = tid >> 6;             // 0..3
  const int l   = tid & 63;
  const int cl  = l & 15;
  const int kg  = l >> 4;

  // ---- load h tile 32x128 fp32 -> two bf16 B-frag sets ----
  bf16x8 pa[4], pb[4];
  const float* ha = out + O_H + ((size_t)t * BB + b0 + cl) * 128;
  const float* hb = ha + 16 * 128;
#pragma unroll
  for (int s = 0; s < 4; s++) {
    f32x4 a0 = *(const f32x4*)&ha[32 * s + 8 * kg];
    f32x4 a1 = *(const f32x4*)&ha[32 * s + 8 * kg + 4];
    f32x4 b0v = *(const f32x4*)&hb[32 * s + 8 * kg];
    f32x4 b1v = *(const f32x4*)&hb[32 * s + 8 * kg + 4];
    pa[s] = (bf16x8){(bf16_t)a0[0], (bf16_t)a0[1], (bf16_t)a0[2], (bf16_t)a0[3],
                     (bf16_t)a1[0], (bf16_t)a1[1], (bf16_t)a1[2], (bf16_t)a1[3]};
    pb[s] = (bf16x8){(bf16_t)b0v[0], (bf16_t)b0v[1], (bf16_t)b0v[2], (bf16_t)b0v[3],
                     (bf16_t)b1v[0], (bf16_t)b1v[1], (bf16_t)b1v[2], (bf16_t)b1v[3]};
  }

  // ---- bo: 4 output tiles per wave, both batch halves ----
#pragma unroll
  for (int i = 0; i < 4; i++) {
    f32x4 aa = {0.f, 0.f, 0.f, 0.f}, ab = {0.f, 0.f, 0.f, 0.f};
#pragma unroll
    for (int s = 0; s < 4; s++) {
      bf16x8 fw = *(const bf16x8*)(ws + WS_WB + (size_t)((hw * 4 + i) * 4 + s) * 512 + l * 8);
      aa = MFMA16(fw, pa[s], aa);
      ab = MFMA16(fw, pb[s], ab);
    }
    *(f32x4*)&stg[cl][(hw * 4 + i) * 16 + 4 * kg]      = aa;
    *(f32x4*)&stg[cl + 16][(hw * 4 + i) * 16 + 4 * kg] = ab;
  }
  asm volatile("s_waitcnt lgkmcnt(0)" ::: "memory");
  __builtin_amdgcn_s_barrier();

  {                                      // coalesced bo store: 32 KB contiguous
    int row = tid >> 3, col = (tid & 7) * 32;
    size_t base = O_BO + ((size_t)t * BB + b0 + row) * 256 + col;
#pragma unroll
    for (int k2 = 0; k2 < 8; k2++) {
      f32x4 v = *(const f32x4*)&stg[row][col + 4 * k2];
      nt_store4(&out[base + 4 * k2], v);
    }
  }
  asm volatile("s_waitcnt lgkmcnt(0)" ::: "memory");
  __builtin_amdgcn_s_barrier();

  // ---- pc (+bias) and hd ----
#pragma unroll
  for (int i = 0; i < 4; i++) {
    f32x4 bias = *(const f32x4*)&bpc[(hw * 4 + i) * 16 + 4 * kg];
    f32x4 aa = bias, ab = bias;
#pragma unroll
    for (int s = 0; s < 4; s++) {
      bf16x8 fw = *(const bf16x8*)(ws + WS_WPF + (size_t)((hw * 4 + i) * 4 + s) * 512 + l * 8);
      aa = MFMA16(fw, pa[s], aa);
      ab = MFMA16(fw, pb[s], ab);
    }
    *(f32x4*)&stg[cl][(hw * 4 + i) * 16 + 4 * kg]      = aa;
    *(f32x4*)&stg[cl + 16][(hw * 4 + i) * 16 + 4 * kg] = ab;
  }
  if (hw == 0) {
    f32x4 bias = (kg < 3) ? *(const f32x4*)&bhd[4 * kg] : (f32x4){0.f, 0.f, 0.f, 0.f};
    f32x4 aa = bias, ab = bias;
#pragma unroll
    for (int s = 0; s < 4; s++) {
      bf16x8 fw = *(const bf16x8*)(ws + WS_WHF + (size_t)s * 512 + l * 8);
      aa = MFMA16(fw, pa[s], aa);
      ab = MFMA16(fw, pb[s], ab);
    }
    if (kg < 3) {
      *(f32x4*)&hdst[cl * 12 + 4 * kg]        = aa;
      *(f32x4*)&hdst[(cl + 16) * 12 + 4 * kg] = ab;
    }
  }
  asm volatile("s_waitcnt lgkmcnt(0)" ::: "memory");
  __builtin_amdgcn_s_barrier();

  {                                      // coalesced pc store: 32 KB contiguous
    int row = tid >> 3, col = (tid & 7) * 32;
    size_t base = O_PC + ((size_t)t * BB + b0 + row) * 256 + col;
#pragma unroll
    for (int k2 = 0; k2 < 8; k2++) {
      f32x4 v = *(const f32x4*)&stg[row][col + 4 * k2];
      nt_store4(&out[base + 4 * k2], v);
    }
  }
  if (tid < 96) {                        // hd store: 1.5 KB contiguous
    f32x4 v = *(const f32x4*)&hdst[tid * 4];
    nt_store4(&out[O_HD + ((size_t)t * BB + b0) * 12 + tid * 4], v);
  }
}

// ---------------------------------------------------------------------------
extern "C" void kernel_launch(void* const* d_in, const int* in_sizes, int n_in,
                              void* d_out, int out_size, void* d_ws, size_t ws_size,
                              hipStream_t stream) {
  const float* x   = (const float*)d_in[0];
  const float* ini = (const float*)d_in[1];
  const float* W   = (const float*)d_in[2];
  const float* U   = (const float*)d_in[3];
  const float* b   = (const float*)d_in[4];
  const float* Wh  = (const float*)d_in[5];
  const float* bh  = (const float*)d_in[6];
  const float* Wc  = (const float*)d_in[7];
  const float* bc  = (const float*)d_in[8];
  const float* Wb  = (const float*)d_in[9];
  const float* Wpc = (const float*)d_in[10];
  const float* bpc = (const float*)d_in[11];
  const float* Whd = (const float*)d_in[12];
  const float* bhd = (const float*)d_in[13];
  float* out = (float*)d_out;
  bf16_t* ws = (bf16_t*)d_ws;   // 149504 bf16 = 292 KB

  hipLaunchKernelGGL(prep_kernel, dim3(124), dim3(256), 0, stream, U, W, b, Wb, Wpc, Whd, ws);
  hipLaunchKernelGGL(lstm_rec, dim3(256), dim3(512), 0, stream,
                     x, ini, Wh, bh, Wc, bc, ws, out);
  hipLaunchKernelGGL(heads_kernel, dim3(6400), dim3(256), 0, stream,
                     bpc, bhd, ws, out);
}

// Round 4
// 325.918 us; speedup vs baseline: 4.0981x; 4.0981x over previous
//
#include <hip/hip_runtime.h>

// ---------------------------------------------------------------------------
// Round 19: fix heads_kernel coalescing (r18 bug: 16B-per-lane @128B-stride
// nt stores -> 3.2x write amplification, 1.3 TB/s). Now:
//  - h tile: contiguous 16KB global read staged via LDS (1KB/wave/instr).
//  - bo/pc: flat f = i*1024 + tid*4 -> 1KB contiguous per wave instruction,
//    32KB contiguous slab per block, block order = memory order (sweep).
// rec kernel and prep unchanged from r18.
// MFMA 16x16x32 bf16 (m89): A: row=l&15,k=8*(l>>4)+j; B: col=l&15 (batch);
// C/D: col=l&15 (batch), row=4*(l>>4)+j (feature).
// ---------------------------------------------------------------------------

typedef __bf16 bf16_t;
typedef __bf16 bf16x4 __attribute__((ext_vector_type(4)));
typedef __bf16 bf16x8 __attribute__((ext_vector_type(8)));
typedef float  f32x4  __attribute__((ext_vector_type(4)));

static_assert(sizeof(bf16x8) == 16, "bf16x8 must be 16B");

#define MFMA16(a, b, c) __builtin_amdgcn_mfma_f32_16x16x32_bf16((a), (b), (c), 0, 0, 0)

constexpr int TT = 100, BB = 2048;
constexpr long O_HD = 0;
constexpr long O_PC = O_HD + (long)TT * BB * 12;    // 2,457,600
constexpr long O_BO = O_PC + (long)TT * BB * 256;   // 54,886,400
constexpr long O_H  = O_BO + (long)TT * BB * 256;   // 107,315,200
constexpr long O_C  = O_H  + (long)TT * BB * 128;   // 133,529,600

// d_ws bf16 frag layout (A-operand order: entry = M[k][out_feature]):
constexpr int WS_U   = 0;        // 32 tiles x 5 s x 512 = 81920 (k128-130=W, k131=b)
constexpr int WS_WB  = 81920;    // 16 tiles x 4 s x 512 = 32768
constexpr int WS_WPF = 114688;   // fused Wb@Wpc: 16 tiles x 4 s x 512 = 32768
constexpr int WS_WHF = 147456;   // fused Wb@Whd: 1 tile x 4 s x 512 = 2048

__device__ __forceinline__ float fast_sigmoid(float x) {
  return __builtin_amdgcn_rcpf(1.0f + __builtin_amdgcn_exp2f(-1.442695040888963f * x));
}
__device__ __forceinline__ float fast_tanh(float x) {
  float e = __builtin_amdgcn_exp2f(2.885390081777927f * x);  // exp(2x)
  return 1.0f - 2.0f * __builtin_amdgcn_rcpf(e + 1.0f);
}

__device__ __forceinline__ void nt_store4(float* p, f32x4 v) {
  __builtin_nontemporal_store(v, (f32x4*)p);
}

// ---------------------------------------------------------------------------
// prep v2 (unchanged): blocks 0-39 U-aug repack; 40-55 Wb repack; 56-119
// Wb@Wpc fusion; 120-123 Wb@Whd fusion.
// ---------------------------------------------------------------------------
__global__ void prep_kernel(const float* __restrict__ U, const float* __restrict__ W,
                            const float* __restrict__ b_, const float* __restrict__ Wb,
                            const float* __restrict__ Wpc, const float* __restrict__ Whd,
                            bf16_t* __restrict__ ws) {
  const int blk = blockIdx.x, tid = threadIdx.x;
  if (blk < 40) {                        // U augmented: 32 tiles x 5 K-slices
    int g = blk * 256 + tid;
    int tile = g / 320, rem = g % 320, s = rem >> 6, l = rem & 63;
    int cl = l & 15, kg = l >> 4, fb = tile * 16;
    bf16x8 v;
#pragma unroll
    for (int j = 0; j < 8; j++) {
      int k = 32 * s + 8 * kg + j;
      float e = 0.0f;
      if (k < 128) e = U[(size_t)k * 512 + fb + cl];
      else if (k < 131) e = W[(size_t)(k - 128) * 512 + fb + cl];
      else if (k == 131) e = b_[fb + cl];
      v[j] = (bf16_t)e;
    }
    *(bf16x8*)(ws + WS_U + (size_t)g * 8) = v;
  } else if (blk < 56) {                 // Wb^T frags: 16 tiles x 4 s
    int gg = (blk - 40) * 256 + tid;
    int tile = gg >> 8, s = (gg >> 6) & 3, l = gg & 63;
    int cl = l & 15, kg = l >> 4;
    bf16x8 v;
#pragma unroll
    for (int j = 0; j < 8; j++)
      v[j] = (bf16_t)Wb[(size_t)(32 * s + 8 * kg + j) * 256 + tile * 16 + cl];
    *(bf16x8*)(ws + WS_WB + (size_t)gg * 8) = v;
  } else if (blk < 120) {                // fused (Wb@Wpc)^T: one (tile,s)/block
    __shared__ float wpcol[256][17];
    int c = blk - 56, tile = c >> 2, s = c & 3;
    for (int i = tid; i < 4096; i += 256)
      wpcol[i >> 4][i & 15] = Wpc[(size_t)(i >> 4) * 256 + tile * 16 + (i & 15)];
    __syncthreads();
    int l = tid & 63, jp = tid >> 6;     // jp in 0..3 -> j = 2jp, 2jp+1
    int cl = l & 15, kg = l >> 4;
    const float* wb0 = Wb + (size_t)(32 * s + 8 * kg + 2 * jp) * 256;
    const float* wb1 = wb0 + 256;
    float d0 = 0.f, d1 = 0.f;
#pragma unroll 8
    for (int n = 0; n < 256; n++) {
      float wv = wpcol[n][cl];
      d0 += wb0[n] * wv;
      d1 += wb1[n] * wv;
    }
    bf16_t* dst = ws + WS_WPF + ((size_t)(tile * 4 + s) * 64 + l) * 8 + 2 * jp;
    dst[0] = (bf16_t)d0;
    dst[1] = (bf16_t)d1;
  } else {                               // fused (Wb@Whd)^T: one s/block (4)
    __shared__ float wpcol[256][17];
    int s = blk - 120;
    for (int i = tid; i < 4096; i += 256) {
      int n = i >> 4, p = i & 15;
      wpcol[n][p] = (p < 12) ? Whd[(size_t)n * 12 + p] : 0.0f;
    }
    __syncthreads();
    int l = tid & 63, jp = tid >> 6;
    int cl = l & 15, kg = l >> 4;
    const float* wb0 = Wb + (size_t)(32 * s + 8 * kg + 2 * jp) * 256;
    const float* wb1 = wb0 + 256;
    float d0 = 0.f, d1 = 0.f;
#pragma unroll 8
    for (int n = 0; n < 256; n++) {
      float wv = wpcol[n][cl];
      d0 += wb0[n] * wv;
      d1 += wb1[n] * wv;
    }
    bf16_t* dst = ws + WS_WHF + ((size_t)s * 64 + l) * 8 + 2 * jp;
    dst[0] = (bf16_t)d0;
    dst[1] = (bf16_t)d1;
  }
}

// ---------------------------------------------------------------------------
// kernel1: recurrence only. 256 blocks x 512 threads (8 gate waves).
// Writes h (fp32, from bf16 values) and c (fp32) only. (unchanged from r18)
// ---------------------------------------------------------------------------
__global__ __launch_bounds__(512, 2) void lstm_rec(
    const float* __restrict__ x, const float* __restrict__ ini,
    const float* __restrict__ Wh, const float* __restrict__ bh,
    const float* __restrict__ Wc, const float* __restrict__ bc,
    const bf16_t* __restrict__ ws, float* __restrict__ out) {
  __shared__ bf16_t hl[2][16][168];     // h(0:128)|x(128:131)|0; rows 8-15 zero
  __shared__ bf16_t xbl[TT][8][4];      // {x0,x1,x2,1.0} per (t,row), 6.25 KB
  __shared__ float  il[8][268];
  __shared__ float  cstg[2][8][132];    // fp32 c staging (dbuf), 8.25 KB

  const int tid = threadIdx.x;
  const int w   = tid >> 6;             // 0..7
  const int l   = tid & 63;
  const int cl  = l & 15;
  const int kg  = l >> 4;
  const int gb0 = blockIdx.x * 8;

  // ---- cooperative LDS init ----
  for (int i = tid; i < 2 * 16 * 168; i += 512) ((bf16_t*)hl)[i] = (bf16_t)0.f;
  for (int i = tid; i < TT * 8; i += 512) {
    int t = i >> 3, r = i & 7;
    const float* xp = x + ((size_t)t * BB + gb0 + r) * 3;
    bf16x4 v = {(bf16_t)xp[0], (bf16_t)xp[1], (bf16_t)xp[2], (bf16_t)1.0f};
    *(bf16x4*)&xbl[t][r][0] = v;
  }
  for (int i = tid; i < 8 * 268; i += 512) {
    int r = i / 268, k = i - r * 268;
    il[r][k] = ini[(size_t)(gb0 + r) * 268 + k];
  }
  __syncthreads();

  const int fb4 = w * 16 + 4 * kg;      // 4 consecutive h-features owned

  // h/c store assignment: even wave -> h quarter, odd wave -> c quarter
  const int q    = w >> 1;              // quarter 0..3
  const int sf   = q * 256 + l * 4;     // flat float index in 8x128 region
  const int srow = sf >> 7;             // 2q or 2q+1
  const int scol = sf & 127;
  float* sptr = out + ((w & 1) ? O_C : O_H) + (size_t)gb0 * 128 + sf;  // tm=0

  bf16x8 uf[4][5];
#pragma unroll
  for (int n = 0; n < 4; n++)
#pragma unroll
    for (int s = 0; s < 5; s++)
      uf[n][s] = *(const bf16x8*)(ws + WS_U + (size_t)((n * 8 + w) * 5 + s) * 512 + l * 8);

  // ---- h0/c0 = init @ Wh/Wc + bh/bc ----
  f32x4 cst;
  {
    f32x4 ha = *(const f32x4*)&bh[fb4];
    f32x4 ca = *(const f32x4*)&bc[fb4];
    for (int k = 0; k < 268; k++) {
      float iv = il[cl & 7][k];
      ha += iv * *(const f32x4*)&Wh[(size_t)k * 128 + fb4];
      ca += iv * *(const f32x4*)&Wc[(size_t)k * 128 + fb4];
    }
    cst = ca;
    if (cl < 8) {
      bf16x4 hv = {(bf16_t)ha[0], (bf16_t)ha[1], (bf16_t)ha[2], (bf16_t)ha[3]};
      *(bf16x4*)&hl[0][cl][fb4] = hv;
    }
  }
  if (tid < 8) *(bf16x4*)&hl[0][tid][128] = *(const bf16x4*)&xbl[0][tid][0];
  asm volatile("s_waitcnt lgkmcnt(0)" ::: "memory");
  __builtin_amdgcn_s_barrier();

  for (int t = 0; t <= TT; t++) {
    // ---- store h(t-1) or c(t-1): one 1KB burst per wave ----
    if (t >= 1) {
      int tm = t - 1;
      if (w & 1) {
        f32x4 vc = *(const f32x4*)&cstg[tm & 1][srow][scol];
        nt_store4(sptr, vc);
      } else {
        // h(t-1) lives in hl[t&1] (bf16); lossless fp32 round trip
        bf16x4 hb = *(const bf16x4*)&hl[t & 1][srow][scol];
        f32x4 vh = {(float)hb[0], (float)hb[1], (float)hb[2], (float)hb[3]};
        nt_store4(sptr, vh);
      }
      sptr += (size_t)BB * 128;
    }
    if (t < TT) {
      bf16x8 hfrag[5];
#pragma unroll
      for (int s = 0; s < 5; s++) hfrag[s] = *(const bf16x8*)&hl[t & 1][cl][32 * s + 8 * kg];

      // split accumulator chains: depth 3 + depth 2, then add
      f32x4 acc[4], acc2[4];
#pragma unroll
      for (int n = 0; n < 4; n++) {
        acc[n]  = (f32x4){0.f, 0.f, 0.f, 0.f};
        acc2[n] = (f32x4){0.f, 0.f, 0.f, 0.f};
      }
#pragma unroll
      for (int s = 0; s < 3; s++)
#pragma unroll
        for (int n = 0; n < 4; n++) acc[n] = MFMA16(uf[n][s], hfrag[s], acc[n]);
#pragma unroll
      for (int s = 3; s < 5; s++)
#pragma unroll
        for (int n = 0; n < 4; n++) acc2[n] = MFMA16(uf[n][s], hfrag[s], acc2[n]);
#pragma unroll
      for (int n = 0; n < 4; n++) acc[n] += acc2[n];

      f32x4 hv4;
#pragma unroll
      for (int j = 0; j < 4; j++) {
        float iv = fast_sigmoid(acc[0][j]);
        float fv = fast_sigmoid(acc[1][j]);
        float gv = fast_tanh(acc[2][j]);
        float ov = fast_sigmoid(acc[3][j]);
        float cv = fv * cst[j] + iv * gv;
        cst[j] = cv;
        hv4[j] = ov * fast_tanh(cv);
      }
      if (cl < 8) {
        bf16x4 hb = {(bf16_t)hv4[0], (bf16_t)hv4[1], (bf16_t)hv4[2], (bf16_t)hv4[3]};
        *(bf16x4*)&hl[(t + 1) & 1][cl][fb4] = hb;
        *(f32x4*)&cstg[t & 1][cl][fb4] = cst;
      }
      if (tid < 8 && t + 1 < TT)
        *(bf16x4*)&hl[(t + 1) & 1][tid][128] = *(const bf16x4*)&xbl[t + 1][tid][0];
    }
    asm volatile("s_waitcnt lgkmcnt(0)" ::: "memory");
    __builtin_amdgcn_s_barrier();
    __builtin_amdgcn_sched_barrier(0);
  }
}

// ---------------------------------------------------------------------------
// kernel2: heads. One block per (t, 32-batch-row) tile: 6400 blocks x 256 thr.
// r19: contiguous LDS-staged h load; flat coalesced slab stores (1KB/wave).
// ---------------------------------------------------------------------------
__global__ __launch_bounds__(256, 3) void heads_kernel(
    const float* __restrict__ bpc, const float* __restrict__ bhd,
    const bf16_t* __restrict__ ws, float* __restrict__ out) {
  __shared__ float hstage[32][132];     // 16.9 KB fp32 h tile (pad 4)
  __shared__ float stg[32][260];        // 33.3 KB bo/pc staging
  __shared__ float hdst[392];           // 32x12 hd staging + pad

  const int idx = blockIdx.x;
  const int t   = idx >> 6;
  const int b0  = (idx & 63) * 32;
  const int tid = threadIdx.x;
  const int hw  = tid >> 6;             // 0..3
  const int l   = tid & 63;
  const int cl  = l & 15;
  const int kg  = l >> 4;

  // ---- coalesced load of contiguous 16KB h tile -> LDS ----
  const float* hsrc = out + O_H + ((size_t)t * BB + b0) * 128;
#pragma unroll
  for (int i = 0; i < 4; i++) {
    int f = i * 1024 + tid * 4;          // flat float idx; 1KB/wave/instr
    f32x4 v = *(const f32x4*)&hsrc[f];
    *(f32x4*)&hstage[f >> 7][f & 127] = v;
  }
  __syncthreads();

  // ---- B-frags from LDS (bf16 round-trip is lossless) ----
  bf16x8 pa[4], pb[4];
#pragma unroll
  for (int s = 0; s < 4; s++) {
    f32x4 a0  = *(const f32x4*)&hstage[cl][32 * s + 8 * kg];
    f32x4 a1  = *(const f32x4*)&hstage[cl][32 * s + 8 * kg + 4];
    f32x4 b0v = *(const f32x4*)&hstage[cl + 16][32 * s + 8 * kg];
    f32x4 b1v = *(const f32x4*)&hstage[cl + 16][32 * s + 8 * kg + 4];
    pa[s] = (bf16x8){(bf16_t)a0[0], (bf16_t)a0[1], (bf16_t)a0[2], (bf16_t)a0[3],
                     (bf16_t)a1[0], (bf16_t)a1[1], (bf16_t)a1[2], (bf16_t)a1[3]};
    pb[s] = (bf16x8){(bf16_t)b0v[0], (bf16_t)b0v[1], (bf16_t)b0v[2], (bf16_t)b0v[3],
                     (bf16_t)b1v[0], (bf16_t)b1v[1], (bf16_t)b1v[2], (bf16_t)b1v[3]};
  }

  // ---- bo: 4 output tiles per wave, both batch halves ----
#pragma unroll
  for (int i = 0; i < 4; i++) {
    f32x4 aa = {0.f, 0.f, 0.f, 0.f}, ab = {0.f, 0.f, 0.f, 0.f};
#pragma unroll
    for (int s = 0; s < 4; s++) {
      bf16x8 fw = *(const bf16x8*)(ws + WS_WB + (size_t)((hw * 4 + i) * 4 + s) * 512 + l * 8);
      aa = MFMA16(fw, pa[s], aa);
      ab = MFMA16(fw, pb[s], ab);
    }
    *(f32x4*)&stg[cl][(hw * 4 + i) * 16 + 4 * kg]      = aa;
    *(f32x4*)&stg[cl + 16][(hw * 4 + i) * 16 + 4 * kg] = ab;
  }
  asm volatile("s_waitcnt lgkmcnt(0)" ::: "memory");
  __builtin_amdgcn_s_barrier();

  {                                      // coalesced bo store: 32KB slab, 1KB/wave/instr
    float* dst = out + O_BO + ((size_t)t * BB + b0) * 256;
#pragma unroll
    for (int i = 0; i < 8; i++) {
      int f = i * 1024 + tid * 4;
      f32x4 v = *(const f32x4*)&stg[f >> 8][f & 255];
      nt_store4(&dst[f], v);
    }
  }
  asm volatile("s_waitcnt lgkmcnt(0)" ::: "memory");
  __builtin_amdgcn_s_barrier();

  // ---- pc (+bias) and hd ----
#pragma unroll
  for (int i = 0; i < 4; i++) {
    f32x4 bias = *(const f32x4*)&bpc[(hw * 4 + i) * 16 + 4 * kg];
    f32x4 aa = bias, ab = bias;
#pragma unroll
    for (int s = 0; s < 4; s++) {
      bf16x8 fw = *(const bf16x8*)(ws + WS_WPF + (size_t)((hw * 4 + i) * 4 + s) * 512 + l * 8);
      aa = MFMA16(fw, pa[s], aa);
      ab = MFMA16(fw, pb[s], ab);
    }
    *(f32x4*)&stg[cl][(hw * 4 + i) * 16 + 4 * kg]      = aa;
    *(f32x4*)&stg[cl + 16][(hw * 4 + i) * 16 + 4 * kg] = ab;
  }
  if (hw == 0) {
    f32x4 bias = (kg < 3) ? *(const f32x4*)&bhd[4 * kg] : (f32x4){0.f, 0.f, 0.f, 0.f};
    f32x4 aa = bias, ab = bias;
#pragma unroll
    for (int s = 0; s < 4; s++) {
      bf16x8 fw = *(const bf16x8*)(ws + WS_WHF + (size_t)s * 512 + l * 8);
      aa = MFMA16(fw, pa[s], aa);
      ab = MFMA16(fw, pb[s], ab);
    }
    if (kg < 3) {
      *(f32x4*)&hdst[cl * 12 + 4 * kg]        = aa;
      *(f32x4*)&hdst[(cl + 16) * 12 + 4 * kg] = ab;
    }
  }
  asm volatile("s_waitcnt lgkmcnt(0)" ::: "memory");
  __builtin_amdgcn_s_barrier();

  {                                      // coalesced pc store: 32KB slab
    float* dst = out + O_PC + ((size_t)t * BB + b0) * 256;
#pragma unroll
    for (int i = 0; i < 8; i++) {
      int f = i * 1024 + tid * 4;
      f32x4 v = *(const f32x4*)&stg[f >> 8][f & 255];
      nt_store4(&dst[f], v);
    }
  }
  if (tid < 96) {                        // hd store: 1.5 KB contiguous
    f32x4 v = *(const f32x4*)&hdst[tid * 4];
    nt_store4(&out[O_HD + ((size_t)t * BB + b0) * 12 + tid * 4], v);
  }
}

// ---------------------------------------------------------------------------
extern "C" void kernel_launch(void* const* d_in, const int* in_sizes, int n_in,
                              void* d_out, int out_size, void* d_ws, size_t ws_size,
                              hipStream_t stream) {
  const float* x   = (const float*)d_in[0];
  const float* ini = (const float*)d_in[1];
  const float* W   = (const float*)d_in[2];
  const float* U   = (const float*)d_in[3];
  const float* b   = (const float*)d_in[4];
  const float* Wh  = (const float*)d_in[5];
  const float* bh  = (const float*)d_in[6];
  const float* Wc  = (const float*)d_in[7];
  const float* bc  = (const float*)d_in[8];
  const float* Wb  = (const float*)d_in[9];
  const float* Wpc = (const float*)d_in[10];
  const float* bpc = (const float*)d_in[11];
  const float* Whd = (const float*)d_in[12];
  const float* bhd = (const float*)d_in[13];
  float* out = (float*)d_out;
  bf16_t* ws = (bf16_t*)d_ws;   // 149504 bf16 = 292 KB

  hipLaunchKernelGGL(prep_kernel, dim3(124), dim3(256), 0, stream, U, W, b, Wb, Wpc, Whd, ws);
  hipLaunchKernelGGL(lstm_rec, dim3(256), dim3(512), 0, stream,
                     x, ini, Wh, bh, Wc, bc, ws, out);
  hipLaunchKernelGGL(heads_kernel, dim3(6400), dim3(256), 0, stream,
                     bpc, bhd, ws, out);
}

// Round 5
// 169.819 us; speedup vs baseline: 7.8651x; 1.9192x over previous
//
#include <hip/hip_runtime.h>

// ---------------------------------------------------------------------------
// Round 20: REVERT to r17 fused kernel (170.9 µs best) + s_setprio(1) around
// the gates waves' critical section (MFMA chain + activations). r18/r19 split
// experiment failed (325 µs): split serializes recurrence and store drain
// that the fused kernel overlaps. Theory here: gate waves (recurrence
// critical path, ~640cy/SIMD/step of quarter-rate trans ops) lose SIMD issue
// slots to head waves' store/LDS traffic; setprio biases arbitration toward
// the critical path (T5: proven +4-7% on role-split attn, null only on
// lockstep GEMM — we have role-split).
// Everything else identical to r17: 256 blocks x 768 thr, waves 0-7 gates /
// 8-11 heads, h/c stores on gate waves, nt stores on all outputs, fused
// pc/hd weights, K-augmented gate MFMA, one barrier per window.
// MFMA 16x16x32 bf16 (m89): C/D: col=l&15 (batch), row=4*(l>>4)+j (feature).
// ---------------------------------------------------------------------------

typedef __bf16 bf16_t;
typedef __bf16 bf16x4 __attribute__((ext_vector_type(4)));
typedef __bf16 bf16x8 __attribute__((ext_vector_type(8)));
typedef float  f32x4  __attribute__((ext_vector_type(4)));

static_assert(sizeof(bf16x8) == 16, "bf16x8 must be 16B");

#define MFMA16(a, b, c) __builtin_amdgcn_mfma_f32_16x16x32_bf16((a), (b), (c), 0, 0, 0)

constexpr int TT = 100, BB = 2048;
constexpr long O_HD = 0;
constexpr long O_PC = O_HD + (long)TT * BB * 12;    // 2,457,600
constexpr long O_BO = O_PC + (long)TT * BB * 256;   // 54,886,400
constexpr long O_H  = O_BO + (long)TT * BB * 256;   // 107,315,200
constexpr long O_C  = O_H  + (long)TT * BB * 128;   // 133,529,600

// d_ws bf16 frag layout (A-operand order: entry = M[k][out_feature]):
constexpr int WS_U   = 0;        // 32 tiles x 5 s x 512 = 81920 (k128-130=W, k131=b)
constexpr int WS_WB  = 81920;    // 16 tiles x 4 s x 512 = 32768
constexpr int WS_WPF = 114688;   // fused Wb@Wpc: 16 tiles x 4 s x 512 = 32768
constexpr int WS_WHF = 147456;   // fused Wb@Whd: 1 tile x 4 s x 512 = 2048

__device__ __forceinline__ float fast_sigmoid(float x) {
  return __builtin_amdgcn_rcpf(1.0f + __builtin_amdgcn_exp2f(-1.442695040888963f * x));
}
__device__ __forceinline__ float fast_tanh(float x) {
  float e = __builtin_amdgcn_exp2f(2.885390081777927f * x);  // exp(2x)
  return 1.0f - 2.0f * __builtin_amdgcn_rcpf(e + 1.0f);
}

__device__ __forceinline__ void nt_store4(float* p, f32x4 v) {
  __builtin_nontemporal_store(v, (f32x4*)p);
}

// ---------------------------------------------------------------------------
// prep v2: blocks 0-39 U-aug repack; 40-55 Wb repack; 56-119 Wb@Wpc fusion
// (one (tile,s) combo per block, Wpc cols LDS-tiled, Wb rows broadcast);
// 120-123 Wb@Whd fusion.
// ---------------------------------------------------------------------------
__global__ void prep_kernel(const float* __restrict__ U, const float* __restrict__ W,
                            const float* __restrict__ b_, const float* __restrict__ Wb,
                            const float* __restrict__ Wpc, const float* __restrict__ Whd,
                            bf16_t* __restrict__ ws) {
  const int blk = blockIdx.x, tid = threadIdx.x;
  if (blk < 40) {                        // U augmented: 32 tiles x 5 K-slices
    int g = blk * 256 + tid;
    int tile = g / 320, rem = g % 320, s = rem >> 6, l = rem & 63;
    int cl = l & 15, kg = l >> 4, fb = tile * 16;
    bf16x8 v;
#pragma unroll
    for (int j = 0; j < 8; j++) {
      int k = 32 * s + 8 * kg + j;
      float e = 0.0f;
      if (k < 128) e = U[(size_t)k * 512 + fb + cl];
      else if (k < 131) e = W[(size_t)(k - 128) * 512 + fb + cl];
      else if (k == 131) e = b_[fb + cl];
      v[j] = (bf16_t)e;
    }
    *(bf16x8*)(ws + WS_U + (size_t)g * 8) = v;
  } else if (blk < 56) {                 // Wb^T frags: 16 tiles x 4 s
    int gg = (blk - 40) * 256 + tid;
    int tile = gg >> 8, s = (gg >> 6) & 3, l = gg & 63;
    int cl = l & 15, kg = l >> 4;
    bf16x8 v;
#pragma unroll
    for (int j = 0; j < 8; j++)
      v[j] = (bf16_t)Wb[(size_t)(32 * s + 8 * kg + j) * 256 + tile * 16 + cl];
    *(bf16x8*)(ws + WS_WB + (size_t)gg * 8) = v;
  } else if (blk < 120) {                // fused (Wb@Wpc)^T: one (tile,s)/block
    __shared__ float wpcol[256][17];
    int c = blk - 56, tile = c >> 2, s = c & 3;
    for (int i = tid; i < 4096; i += 256)
      wpcol[i >> 4][i & 15] = Wpc[(size_t)(i >> 4) * 256 + tile * 16 + (i & 15)];
    __syncthreads();
    int l = tid & 63, jp = tid >> 6;     // jp in 0..3 -> j = 2jp, 2jp+1
    int cl = l & 15, kg = l >> 4;
    const float* wb0 = Wb + (size_t)(32 * s + 8 * kg + 2 * jp) * 256;
    const float* wb1 = wb0 + 256;
    float d0 = 0.f, d1 = 0.f;
#pragma unroll 8
    for (int n = 0; n < 256; n++) {
      float wv = wpcol[n][cl];
      d0 += wb0[n] * wv;
      d1 += wb1[n] * wv;
    }
    bf16_t* dst = ws + WS_WPF + ((size_t)(tile * 4 + s) * 64 + l) * 8 + 2 * jp;
    dst[0] = (bf16_t)d0;
    dst[1] = (bf16_t)d1;
  } else {                               // fused (Wb@Whd)^T: one s/block (4)
    __shared__ float wpcol[256][17];
    int s = blk - 120;
    for (int i = tid; i < 4096; i += 256) {
      int n = i >> 4, p = i & 15;
      wpcol[n][p] = (p < 12) ? Whd[(size_t)n * 12 + p] : 0.0f;
    }
    __syncthreads();
    int l = tid & 63, jp = tid >> 6;
    int cl = l & 15, kg = l >> 4;
    const float* wb0 = Wb + (size_t)(32 * s + 8 * kg + 2 * jp) * 256;
    const float* wb1 = wb0 + 256;
    float d0 = 0.f, d1 = 0.f;
#pragma unroll 8
    for (int n = 0; n < 256; n++) {
      float wv = wpcol[n][cl];
      d0 += wb0[n] * wv;
      d1 += wb1[n] * wv;
    }
    bf16_t* dst = ws + WS_WHF + ((size_t)s * 64 + l) * 8 + 2 * jp;
    dst[0] = (bf16_t)d0;
    dst[1] = (bf16_t)d1;
  }
}

// ---------------------------------------------------------------------------
__global__ __launch_bounds__(768, 3) void lstm_fused(
    const float* __restrict__ x, const float* __restrict__ ini,
    const float* __restrict__ Wh, const float* __restrict__ bh,
    const float* __restrict__ Wc, const float* __restrict__ bc,
    const float* __restrict__ bpc, const float* __restrict__ bhd,
    const bf16_t* __restrict__ ws, float* __restrict__ out) {
  __shared__ bf16_t hl[2][16][168];     // h(0:128)|x(128:131)|0; rows 8-15 zero
  __shared__ bf16_t hp[2][16][136];     // pair buf: rows 0-7=h(2k), 8-15=h(2k+1)
  __shared__ bf16_t wpcl[32768];        // fused pc weight frags, 64 KB
  __shared__ bf16_t whdl[2048];         // fused hd weight frags, 4 KB
  __shared__ bf16_t xbl[TT][8][4];      // {x0,x1,x2,1.0} per (t,row), 6.25 KB
  __shared__ float  il[8][268];
  __shared__ float  cstg[2][8][132];    // fp32 c staging (dbuf), 8.25 KB
  __shared__ float  bostg[16][260];     // fp32 bo pair staging, 16.25 KB
  __shared__ float  pcstg[16][260];     // fp32 pc pair staging, 16.25 KB
  __shared__ float  hdstg[2][100];      // fp32 hd pair staging, 0.8 KB

  const int tid = threadIdx.x;
  const int w   = tid >> 6;             // 0..11
  const int l   = tid & 63;
  const int cl  = l & 15;
  const int kg  = l >> 4;
  const int gb0 = blockIdx.x * 8;

  // ---- cooperative LDS init (all 12 waves) ----
  for (int i = tid; i < 2 * 16 * 168; i += 768) ((bf16_t*)hl)[i] = (bf16_t)0.f;
  for (int i = tid; i < TT * 8; i += 768) {
    int t = i >> 3, r = i & 7;
    const float* xp = x + ((size_t)t * BB + gb0 + r) * 3;
    bf16x4 v = {(bf16_t)xp[0], (bf16_t)xp[1], (bf16_t)xp[2], (bf16_t)1.0f};
    *(bf16x4*)&xbl[t][r][0] = v;
  }
  for (int i = tid; i < 8 * 268; i += 768) {
    int r = i / 268, k = i - r * 268;
    il[r][k] = ini[(size_t)(gb0 + r) * 268 + k];
  }
  for (int c = tid; c < 4096; c += 768)
    *(bf16x8*)(wpcl + (size_t)c * 8) = *(const bf16x8*)(ws + WS_WPF + (size_t)c * 8);
  if (tid < 256)
    *(bf16x8*)(whdl + (size_t)tid * 8) = *(const bf16x8*)(ws + WS_WHF + (size_t)tid * 8);
  __syncthreads();

  if (w < 8) {
    // ================= GATES waves (recurrence critical path) =================
    const int fb4 = w * 16 + 4 * kg;    // 4 consecutive h-features owned

    // h/c store assignment: even wave -> h quarter, odd wave -> c quarter
    const int q    = w >> 1;            // quarter 0..3
    const int sf   = q * 256 + l * 4;   // flat float index in 8x128 region
    const int srow = sf >> 7;           // 2q or 2q+1
    const int scol = sf & 127;
    float* sptr = out + ((w & 1) ? O_C : O_H) + (size_t)gb0 * 128 + sf;  // tm=0

    bf16x8 uf[4][5];
#pragma unroll
    for (int n = 0; n < 4; n++)
#pragma unroll
      for (int s = 0; s < 5; s++)
        uf[n][s] = *(const bf16x8*)(ws + WS_U + (size_t)((n * 8 + w) * 5 + s) * 512 + l * 8);

    // ---- h0/c0 = init @ Wh/Wc + bh/bc ----
    f32x4 cst;
    {
      f32x4 ha = *(const f32x4*)&bh[fb4];
      f32x4 ca = *(const f32x4*)&bc[fb4];
      for (int k = 0; k < 268; k++) {
        float iv = il[cl & 7][k];
        ha += iv * *(const f32x4*)&Wh[(size_t)k * 128 + fb4];
        ca += iv * *(const f32x4*)&Wc[(size_t)k * 128 + fb4];
      }
      cst = ca;
      if (cl < 8) {
        bf16x4 hv = {(bf16_t)ha[0], (bf16_t)ha[1], (bf16_t)ha[2], (bf16_t)ha[3]};
        *(bf16x4*)&hl[0][cl][fb4] = hv;
      }
    }
    if (tid < 8) *(bf16x4*)&hl[0][tid][128] = *(const bf16x4*)&xbl[0][tid][0];
    asm volatile("s_waitcnt lgkmcnt(0)" ::: "memory");
    __builtin_amdgcn_s_barrier();

    for (int t = 0; t <= 102; t++) {
      // ---- store h(t-1) or c(t-1): one 1KB burst per wave ----
      if (t >= 1 && t <= TT) {
        int tm = t - 1;
        if (w & 1) {
          f32x4 vc = *(const f32x4*)&cstg[tm & 1][srow][scol];
          nt_store4(sptr, vc);
        } else {
          bf16x4 hb = *(const bf16x4*)&hp[(tm >> 1) & 1][(tm & 1) * 8 + srow][scol];
          f32x4 vh = {(float)hb[0], (float)hb[1], (float)hb[2], (float)hb[3]};
          nt_store4(sptr, vh);
        }
        sptr += (size_t)BB * 128;
      }
      if (t < TT) {
        bf16x8 hfrag[5];
#pragma unroll
        for (int s = 0; s < 5; s++) hfrag[s] = *(const bf16x8*)&hl[t & 1][cl][32 * s + 8 * kg];

        // critical section: boost wave priority through MFMA + activations
        __builtin_amdgcn_s_setprio(1);

        // split accumulator chains: depth 3 + depth 2, then add
        f32x4 acc[4], acc2[4];
#pragma unroll
        for (int n = 0; n < 4; n++) {
          acc[n]  = (f32x4){0.f, 0.f, 0.f, 0.f};
          acc2[n] = (f32x4){0.f, 0.f, 0.f, 0.f};
        }
#pragma unroll
        for (int s = 0; s < 3; s++)
#pragma unroll
          for (int n = 0; n < 4; n++) acc[n] = MFMA16(uf[n][s], hfrag[s], acc[n]);
#pragma unroll
        for (int s = 3; s < 5; s++)
#pragma unroll
          for (int n = 0; n < 4; n++) acc2[n] = MFMA16(uf[n][s], hfrag[s], acc2[n]);
#pragma unroll
        for (int n = 0; n < 4; n++) acc[n] += acc2[n];

        f32x4 hv4;
#pragma unroll
        for (int j = 0; j < 4; j++) {
          float iv = fast_sigmoid(acc[0][j]);
          float fv = fast_sigmoid(acc[1][j]);
          float gv = fast_tanh(acc[2][j]);
          float ov = fast_sigmoid(acc[3][j]);
          float cv = fv * cst[j] + iv * gv;
          cst[j] = cv;
          hv4[j] = ov * fast_tanh(cv);
        }
        if (cl < 8) {
          bf16x4 hb = {(bf16_t)hv4[0], (bf16_t)hv4[1], (bf16_t)hv4[2], (bf16_t)hv4[3]};
          *(bf16x4*)&hl[(t + 1) & 1][cl][fb4] = hb;
          *(bf16x4*)&hp[(t >> 1) & 1][(t & 1) * 8 + cl][fb4] = hb;
          *(f32x4*)&cstg[t & 1][cl][fb4] = cst;
        }
        __builtin_amdgcn_s_setprio(0);
        if (tid < 8 && t + 1 < TT)
          *(bf16x4*)&hl[(t + 1) & 1][tid][128] = *(const bf16x4*)&xbl[t + 1][tid][0];
      }
      asm volatile("s_waitcnt lgkmcnt(0)" ::: "memory");
      __builtin_amdgcn_s_barrier();
      __builtin_amdgcn_sched_barrier(0);
    }
  } else {
    // ============ HEADS waves (bo/pc/hd MFMA + bo/pc/hd stores) ============
    const int hw = w - 8;               // 0..3

    bf16x8 wbv[4][4], wpv[2][4];
#pragma unroll
    for (int i = 0; i < 4; i++)
#pragma unroll
      for (int s = 0; s < 4; s++)
        wbv[i][s] = *(const bf16x8*)(ws + WS_WB + (size_t)((hw * 4 + i) * 4 + s) * 512 + l * 8);
#pragma unroll
    for (int i = 0; i < 2; i++)
#pragma unroll
      for (int s = 0; s < 4; s++)
        wpv[i][s] = *(const bf16x8*)(ws + WS_WPF + (size_t)((hw * 4 + i) * 4 + s) * 512 + l * 8);
    f32x4 bpcq[4];
#pragma unroll
    for (int i = 0; i < 4; i++) bpcq[i] = *(const f32x4*)&bpc[(hw * 4 + i) * 16 + 4 * kg];
    f32x4 bhdq = (kg < 3) ? *(const f32x4*)&bhd[4 * kg] : (f32x4){0.f, 0.f, 0.f, 0.f};

    asm volatile("s_waitcnt lgkmcnt(0)" ::: "memory");
    __builtin_amdgcn_s_barrier();

    bf16x8 pb[4];                        // pair tile frags, live even->odd window
    for (int t = 0; t <= 102; t++) {
      if (!(t & 1)) {
        // ---- even: compute bo pair(t-2,t-1) -> bostg ----
        if (t >= 2 && t <= TT) {
          int slot = ((t - 2) >> 1) & 1;
#pragma unroll
          for (int s = 0; s < 4; s++) pb[s] = *(const bf16x8*)&hp[slot][cl][32 * s + 8 * kg];
#pragma unroll
          for (int i = 0; i < 4; i++) {
            f32x4 bacc = {0.f, 0.f, 0.f, 0.f};
#pragma unroll
            for (int s = 0; s < 4; s++) bacc = MFMA16(wbv[i][s], pb[s], bacc);
            *(f32x4*)&bostg[cl][(hw * 4 + i) * 16 + 4 * kg] = bacc;
          }
        }
        // ---- even: store pc/hd pair(t-4,t-3) ----
        if (t >= 4) {
          int tp = t - 4;
#pragma unroll
          for (int i = 0; i < 4; i++) {
            int f = (hw * 4 + i) * 256 + l * 4;     // one full row of pcstg
            int row = f >> 8, col = f & 255;
            f32x4 v = *(const f32x4*)&pcstg[row][col];
            size_t r = ((size_t)(tp + (row >> 3)) * BB + gb0 + (row & 7)) * 256;
            nt_store4(&out[O_PC + r + col], v);
          }
          if (hw == 0 && l < 48) {
            int s2 = l / 24, li = l % 24;
            f32x4 v = *(const f32x4*)&hdstg[s2][li * 4];
            nt_store4(&out[O_HD + ((size_t)(tp + s2) * BB + gb0) * 12 + li * 4], v);
          }
        }
      } else {
        // ---- odd: compute pc/hd pair(t-3,t-2) -> pcstg/hdstg; store bo ----
        if (t >= 3 && t <= TT + 1) {
#pragma unroll
          for (int i = 0; i < 4; i++) {
            f32x4 pacc = bpcq[i];
            if (i < 2) {
#pragma unroll
              for (int s = 0; s < 4; s++) pacc = MFMA16(wpv[i][s], pb[s], pacc);
            } else {
#pragma unroll
              for (int s = 0; s < 4; s++) {
                bf16x8 fw = *(const bf16x8*)(wpcl + (size_t)((hw * 4 + i) * 4 + s) * 512 + l * 8);
                pacc = MFMA16(fw, pb[s], pacc);
              }
            }
            *(f32x4*)&pcstg[cl][(hw * 4 + i) * 16 + 4 * kg] = pacc;
          }
          if (hw == 0) {
            f32x4 hacc = bhdq;
#pragma unroll
            for (int s = 0; s < 4; s++) {
              bf16x8 fw = *(const bf16x8*)(whdl + (size_t)s * 512 + l * 8);
              hacc = MFMA16(fw, pb[s], hacc);
            }
            if (kg < 3) *(f32x4*)&hdstg[cl >> 3][(cl & 7) * 12 + 4 * kg] = hacc;
          }
          int tp = t - 3;
#pragma unroll
          for (int i = 0; i < 4; i++) {
            int f = (hw * 4 + i) * 256 + l * 4;     // one full row of bostg
            int row = f >> 8, col = f & 255;
            f32x4 v = *(const f32x4*)&bostg[row][col];
            size_t r = ((size_t)(tp + (row >> 3)) * BB + gb0 + (row & 7)) * 256;
            nt_store4(&out[O_BO + r + col], v);
          }
        }
      }
      asm volatile("s_waitcnt lgkmcnt(0)" ::: "memory");
      __builtin_amdgcn_s_barrier();
      __builtin_amdgcn_sched_barrier(0);
    }
  }
}

// ---------------------------------------------------------------------------
extern "C" void kernel_launch(void* const* d_in, const int* in_sizes, int n_in,
                              void* d_out, int out_size, void* d_ws, size_t ws_size,
                              hipStream_t stream) {
  const float* x   = (const float*)d_in[0];
  const float* ini = (const float*)d_in[1];
  const float* W   = (const float*)d_in[2];
  const float* U   = (const float*)d_in[3];
  const float* b   = (const float*)d_in[4];
  const float* Wh  = (const float*)d_in[5];
  const float* bh  = (const float*)d_in[6];
  const float* Wc  = (const float*)d_in[7];
  const float* bc  = (const float*)d_in[8];
  const float* Wb  = (const float*)d_in[9];
  const float* Wpc = (const float*)d_in[10];
  const float* bpc = (const float*)d_in[11];
  const float* Whd = (const float*)d_in[12];
  const float* bhd = (const float*)d_in[13];
  float* out = (float*)d_out;
  bf16_t* ws = (bf16_t*)d_ws;   // 149504 bf16 = 292 KB

  hipLaunchKernelGGL(prep_kernel, dim3(124), dim3(256), 0, stream, U, W, b, Wb, Wpc, Whd, ws);
  hipLaunchKernelGGL(lstm_fused, dim3(256), dim3(768), 0, stream,
                     x, ini, Wh, bh, Wc, bc, bpc, bhd, ws, out);
}

// Round 6
// 163.917 us; speedup vs baseline: 8.1482x; 1.0360x over previous
//
#include <hip/hip_runtime.h>

// ---------------------------------------------------------------------------
// Round 21: t-loop unrolled x2 (both wave roles). Theory: compiler reuses
// store-data VGPRs every window -> vmcnt wait caps in-flight stores at ~1
// window (~6 MB device-wide); Little's law then caps drain at ~3.8 TB/s
// (measured). Unroll x2 -> two disjoint temp sets -> 2-window reuse distance
// -> ~12 MB in flight -> drain toward fill rate (6.5 TB/s). Ring indices
// become compile-time constants per copy. One extra empty window (t=103)
// keeps barrier counts aligned. Everything else identical to r20 (fused, nt
// stores, setprio on gates critical section, h/c stores on gate waves).
// MFMA 16x16x32 bf16 (m89): C/D: col=l&15 (batch), row=4*(l>>4)+j (feature).
// ---------------------------------------------------------------------------

typedef __bf16 bf16_t;
typedef __bf16 bf16x4 __attribute__((ext_vector_type(4)));
typedef __bf16 bf16x8 __attribute__((ext_vector_type(8)));
typedef float  f32x4  __attribute__((ext_vector_type(4)));

static_assert(sizeof(bf16x8) == 16, "bf16x8 must be 16B");

#define MFMA16(a, b, c) __builtin_amdgcn_mfma_f32_16x16x32_bf16((a), (b), (c), 0, 0, 0)

constexpr int TT = 100, BB = 2048;
constexpr long O_HD = 0;
constexpr long O_PC = O_HD + (long)TT * BB * 12;    // 2,457,600
constexpr long O_BO = O_PC + (long)TT * BB * 256;   // 54,886,400
constexpr long O_H  = O_BO + (long)TT * BB * 256;   // 107,315,200
constexpr long O_C  = O_H  + (long)TT * BB * 128;   // 133,529,600

// d_ws bf16 frag layout (A-operand order: entry = M[k][out_feature]):
constexpr int WS_U   = 0;        // 32 tiles x 5 s x 512 = 81920 (k128-130=W, k131=b)
constexpr int WS_WB  = 81920;    // 16 tiles x 4 s x 512 = 32768
constexpr int WS_WPF = 114688;   // fused Wb@Wpc: 16 tiles x 4 s x 512 = 32768
constexpr int WS_WHF = 147456;   // fused Wb@Whd: 1 tile x 4 s x 512 = 2048

__device__ __forceinline__ float fast_sigmoid(float x) {
  return __builtin_amdgcn_rcpf(1.0f + __builtin_amdgcn_exp2f(-1.442695040888963f * x));
}
__device__ __forceinline__ float fast_tanh(float x) {
  float e = __builtin_amdgcn_exp2f(2.885390081777927f * x);  // exp(2x)
  return 1.0f - 2.0f * __builtin_amdgcn_rcpf(e + 1.0f);
}

__device__ __forceinline__ void nt_store4(float* p, f32x4 v) {
  __builtin_nontemporal_store(v, (f32x4*)p);
}

// ---------------------------------------------------------------------------
// prep v2: blocks 0-39 U-aug repack; 40-55 Wb repack; 56-119 Wb@Wpc fusion
// (one (tile,s) combo per block, Wpc cols LDS-tiled, Wb rows broadcast);
// 120-123 Wb@Whd fusion.
// ---------------------------------------------------------------------------
__global__ void prep_kernel(const float* __restrict__ U, const float* __restrict__ W,
                            const float* __restrict__ b_, const float* __restrict__ Wb,
                            const float* __restrict__ Wpc, const float* __restrict__ Whd,
                            bf16_t* __restrict__ ws) {
  const int blk = blockIdx.x, tid = threadIdx.x;
  if (blk < 40) {                        // U augmented: 32 tiles x 5 K-slices
    int g = blk * 256 + tid;
    int tile = g / 320, rem = g % 320, s = rem >> 6, l = rem & 63;
    int cl = l & 15, kg = l >> 4, fb = tile * 16;
    bf16x8 v;
#pragma unroll
    for (int j = 0; j < 8; j++) {
      int k = 32 * s + 8 * kg + j;
      float e = 0.0f;
      if (k < 128) e = U[(size_t)k * 512 + fb + cl];
      else if (k < 131) e = W[(size_t)(k - 128) * 512 + fb + cl];
      else if (k == 131) e = b_[fb + cl];
      v[j] = (bf16_t)e;
    }
    *(bf16x8*)(ws + WS_U + (size_t)g * 8) = v;
  } else if (blk < 56) {                 // Wb^T frags: 16 tiles x 4 s
    int gg = (blk - 40) * 256 + tid;
    int tile = gg >> 8, s = (gg >> 6) & 3, l = gg & 63;
    int cl = l & 15, kg = l >> 4;
    bf16x8 v;
#pragma unroll
    for (int j = 0; j < 8; j++)
      v[j] = (bf16_t)Wb[(size_t)(32 * s + 8 * kg + j) * 256 + tile * 16 + cl];
    *(bf16x8*)(ws + WS_WB + (size_t)gg * 8) = v;
  } else if (blk < 120) {                // fused (Wb@Wpc)^T: one (tile,s)/block
    __shared__ float wpcol[256][17];
    int c = blk - 56, tile = c >> 2, s = c & 3;
    for (int i = tid; i < 4096; i += 256)
      wpcol[i >> 4][i & 15] = Wpc[(size_t)(i >> 4) * 256 + tile * 16 + (i & 15)];
    __syncthreads();
    int l = tid & 63, jp = tid >> 6;     // jp in 0..3 -> j = 2jp, 2jp+1
    int cl = l & 15, kg = l >> 4;
    const float* wb0 = Wb + (size_t)(32 * s + 8 * kg + 2 * jp) * 256;
    const float* wb1 = wb0 + 256;
    float d0 = 0.f, d1 = 0.f;
#pragma unroll 8
    for (int n = 0; n < 256; n++) {
      float wv = wpcol[n][cl];
      d0 += wb0[n] * wv;
      d1 += wb1[n] * wv;
    }
    bf16_t* dst = ws + WS_WPF + ((size_t)(tile * 4 + s) * 64 + l) * 8 + 2 * jp;
    dst[0] = (bf16_t)d0;
    dst[1] = (bf16_t)d1;
  } else {                               // fused (Wb@Whd)^T: one s/block (4)
    __shared__ float wpcol[256][17];
    int s = blk - 120;
    for (int i = tid; i < 4096; i += 256) {
      int n = i >> 4, p = i & 15;
      wpcol[n][p] = (p < 12) ? Whd[(size_t)n * 12 + p] : 0.0f;
    }
    __syncthreads();
    int l = tid & 63, jp = tid >> 6;
    int cl = l & 15, kg = l >> 4;
    const float* wb0 = Wb + (size_t)(32 * s + 8 * kg + 2 * jp) * 256;
    const float* wb1 = wb0 + 256;
    float d0 = 0.f, d1 = 0.f;
#pragma unroll 8
    for (int n = 0; n < 256; n++) {
      float wv = wpcol[n][cl];
      d0 += wb0[n] * wv;
      d1 += wb1[n] * wv;
    }
    bf16_t* dst = ws + WS_WHF + ((size_t)s * 64 + l) * 8 + 2 * jp;
    dst[0] = (bf16_t)d0;
    dst[1] = (bf16_t)d1;
  }
}

// ---------------------------------------------------------------------------
__global__ __launch_bounds__(768, 3) void lstm_fused(
    const float* __restrict__ x, const float* __restrict__ ini,
    const float* __restrict__ Wh, const float* __restrict__ bh,
    const float* __restrict__ Wc, const float* __restrict__ bc,
    const float* __restrict__ bpc, const float* __restrict__ bhd,
    const bf16_t* __restrict__ ws, float* __restrict__ out) {
  __shared__ bf16_t hl[2][16][168];     // h(0:128)|x(128:131)|0; rows 8-15 zero
  __shared__ bf16_t hp[2][16][136];     // pair buf: rows 0-7=h(2k), 8-15=h(2k+1)
  __shared__ bf16_t wpcl[32768];        // fused pc weight frags, 64 KB
  __shared__ bf16_t whdl[2048];         // fused hd weight frags, 4 KB
  __shared__ bf16_t xbl[TT][8][4];      // {x0,x1,x2,1.0} per (t,row), 6.25 KB
  __shared__ float  il[8][268];
  __shared__ float  cstg[2][8][132];    // fp32 c staging (dbuf), 8.25 KB
  __shared__ float  bostg[16][260];     // fp32 bo pair staging, 16.25 KB
  __shared__ float  pcstg[16][260];     // fp32 pc pair staging, 16.25 KB
  __shared__ float  hdstg[2][100];      // fp32 hd pair staging, 0.8 KB

  const int tid = threadIdx.x;
  const int w   = tid >> 6;             // 0..11
  const int l   = tid & 63;
  const int cl  = l & 15;
  const int kg  = l >> 4;
  const int gb0 = blockIdx.x * 8;

  // ---- cooperative LDS init (all 12 waves) ----
  for (int i = tid; i < 2 * 16 * 168; i += 768) ((bf16_t*)hl)[i] = (bf16_t)0.f;
  for (int i = tid; i < TT * 8; i += 768) {
    int t = i >> 3, r = i & 7;
    const float* xp = x + ((size_t)t * BB + gb0 + r) * 3;
    bf16x4 v = {(bf16_t)xp[0], (bf16_t)xp[1], (bf16_t)xp[2], (bf16_t)1.0f};
    *(bf16x4*)&xbl[t][r][0] = v;
  }
  for (int i = tid; i < 8 * 268; i += 768) {
    int r = i / 268, k = i - r * 268;
    il[r][k] = ini[(size_t)(gb0 + r) * 268 + k];
  }
  for (int c = tid; c < 4096; c += 768)
    *(bf16x8*)(wpcl + (size_t)c * 8) = *(const bf16x8*)(ws + WS_WPF + (size_t)c * 8);
  if (tid < 256)
    *(bf16x8*)(whdl + (size_t)tid * 8) = *(const bf16x8*)(ws + WS_WHF + (size_t)tid * 8);
  __syncthreads();

  if (w < 8) {
    // ================= GATES waves (recurrence critical path) =================
    const int fb4 = w * 16 + 4 * kg;    // 4 consecutive h-features owned

    // h/c store assignment: even wave -> h quarter, odd wave -> c quarter
    const int q    = w >> 1;            // quarter 0..3
    const int sf   = q * 256 + l * 4;   // flat float index in 8x128 region
    const int srow = sf >> 7;           // 2q or 2q+1
    const int scol = sf & 127;
    float* sptr = out + ((w & 1) ? O_C : O_H) + (size_t)gb0 * 128 + sf;  // tm=0

    bf16x8 uf[4][5];
#pragma unroll
    for (int n = 0; n < 4; n++)
#pragma unroll
      for (int s = 0; s < 5; s++)
        uf[n][s] = *(const bf16x8*)(ws + WS_U + (size_t)((n * 8 + w) * 5 + s) * 512 + l * 8);

    // ---- h0/c0 = init @ Wh/Wc + bh/bc ----
    f32x4 cst;
    {
      f32x4 ha = *(const f32x4*)&bh[fb4];
      f32x4 ca = *(const f32x4*)&bc[fb4];
      for (int k = 0; k < 268; k++) {
        float iv = il[cl & 7][k];
        ha += iv * *(const f32x4*)&Wh[(size_t)k * 128 + fb4];
        ca += iv * *(const f32x4*)&Wc[(size_t)k * 128 + fb4];
      }
      cst = ca;
      if (cl < 8) {
        bf16x4 hv = {(bf16_t)ha[0], (bf16_t)ha[1], (bf16_t)ha[2], (bf16_t)ha[3]};
        *(bf16x4*)&hl[0][cl][fb4] = hv;
      }
    }
    if (tid < 8) *(bf16x4*)&hl[0][tid][128] = *(const bf16x4*)&xbl[0][tid][0];
    asm volatile("s_waitcnt lgkmcnt(0)" ::: "memory");
    __builtin_amdgcn_s_barrier();

    auto gate_window = [&](int t) {
      // ---- store h(t-1) or c(t-1): one 1KB burst per wave ----
      if (t >= 1 && t <= TT) {
        int tm = t - 1;
        if (w & 1) {
          f32x4 vc = *(const f32x4*)&cstg[tm & 1][srow][scol];
          nt_store4(sptr, vc);
        } else {
          bf16x4 hb = *(const bf16x4*)&hp[(tm >> 1) & 1][(tm & 1) * 8 + srow][scol];
          f32x4 vh = {(float)hb[0], (float)hb[1], (float)hb[2], (float)hb[3]};
          nt_store4(sptr, vh);
        }
        sptr += (size_t)BB * 128;
      }
      if (t < TT) {
        bf16x8 hfrag[5];
#pragma unroll
        for (int s = 0; s < 5; s++) hfrag[s] = *(const bf16x8*)&hl[t & 1][cl][32 * s + 8 * kg];

        // critical section: boost wave priority through MFMA + activations
        __builtin_amdgcn_s_setprio(1);

        // split accumulator chains: depth 3 + depth 2, then add
        f32x4 acc[4], acc2[4];
#pragma unroll
        for (int n = 0; n < 4; n++) {
          acc[n]  = (f32x4){0.f, 0.f, 0.f, 0.f};
          acc2[n] = (f32x4){0.f, 0.f, 0.f, 0.f};
        }
#pragma unroll
        for (int s = 0; s < 3; s++)
#pragma unroll
          for (int n = 0; n < 4; n++) acc[n] = MFMA16(uf[n][s], hfrag[s], acc[n]);
#pragma unroll
        for (int s = 3; s < 5; s++)
#pragma unroll
          for (int n = 0; n < 4; n++) acc2[n] = MFMA16(uf[n][s], hfrag[s], acc2[n]);
#pragma unroll
        for (int n = 0; n < 4; n++) acc[n] += acc2[n];

        f32x4 hv4;
#pragma unroll
        for (int j = 0; j < 4; j++) {
          float iv = fast_sigmoid(acc[0][j]);
          float fv = fast_sigmoid(acc[1][j]);
          float gv = fast_tanh(acc[2][j]);
          float ov = fast_sigmoid(acc[3][j]);
          float cv = fv * cst[j] + iv * gv;
          cst[j] = cv;
          hv4[j] = ov * fast_tanh(cv);
        }
        if (cl < 8) {
          bf16x4 hb = {(bf16_t)hv4[0], (bf16_t)hv4[1], (bf16_t)hv4[2], (bf16_t)hv4[3]};
          *(bf16x4*)&hl[(t + 1) & 1][cl][fb4] = hb;
          *(bf16x4*)&hp[(t >> 1) & 1][(t & 1) * 8 + cl][fb4] = hb;
          *(f32x4*)&cstg[t & 1][cl][fb4] = cst;
        }
        __builtin_amdgcn_s_setprio(0);
        if (tid < 8 && t + 1 < TT)
          *(bf16x4*)&hl[(t + 1) & 1][tid][128] = *(const bf16x4*)&xbl[t + 1][tid][0];
      }
      asm volatile("s_waitcnt lgkmcnt(0)" ::: "memory");
      __builtin_amdgcn_s_barrier();
      __builtin_amdgcn_sched_barrier(0);
    };

    // unroll x2: disjoint store-temp VGPR sets -> 2-window vmcnt reuse distance
    for (int tb = 0; tb < 104; tb += 2) {
      gate_window(tb);
      gate_window(tb + 1);
    }
  } else {
    // ============ HEADS waves (bo/pc/hd MFMA + bo/pc/hd stores) ============
    const int hw = w - 8;               // 0..3

    bf16x8 wbv[4][4], wpv[2][4];
#pragma unroll
    for (int i = 0; i < 4; i++)
#pragma unroll
      for (int s = 0; s < 4; s++)
        wbv[i][s] = *(const bf16x8*)(ws + WS_WB + (size_t)((hw * 4 + i) * 4 + s) * 512 + l * 8);
#pragma unroll
    for (int i = 0; i < 2; i++)
#pragma unroll
      for (int s = 0; s < 4; s++)
        wpv[i][s] = *(const bf16x8*)(ws + WS_WPF + (size_t)((hw * 4 + i) * 4 + s) * 512 + l * 8);
    f32x4 bpcq[4];
#pragma unroll
    for (int i = 0; i < 4; i++) bpcq[i] = *(const f32x4*)&bpc[(hw * 4 + i) * 16 + 4 * kg];
    f32x4 bhdq = (kg < 3) ? *(const f32x4*)&bhd[4 * kg] : (f32x4){0.f, 0.f, 0.f, 0.f};

    asm volatile("s_waitcnt lgkmcnt(0)" ::: "memory");
    __builtin_amdgcn_s_barrier();

    bf16x8 pb[4];                        // pair tile frags, live even->odd window

    auto heads_even = [&](int t) {
      // ---- even: compute bo pair(t-2,t-1) -> bostg ----
      if (t >= 2 && t <= TT) {
        int slot = ((t - 2) >> 1) & 1;
#pragma unroll
        for (int s = 0; s < 4; s++) pb[s] = *(const bf16x8*)&hp[slot][cl][32 * s + 8 * kg];
#pragma unroll
        for (int i = 0; i < 4; i++) {
          f32x4 bacc = {0.f, 0.f, 0.f, 0.f};
#pragma unroll
          for (int s = 0; s < 4; s++) bacc = MFMA16(wbv[i][s], pb[s], bacc);
          *(f32x4*)&bostg[cl][(hw * 4 + i) * 16 + 4 * kg] = bacc;
        }
      }
      // ---- even: store pc/hd pair(t-4,t-3) ----
      if (t >= 4) {
        int tp = t - 4;
#pragma unroll
        for (int i = 0; i < 4; i++) {
          int f = (hw * 4 + i) * 256 + l * 4;     // one full row of pcstg
          int row = f >> 8, col = f & 255;
          f32x4 v = *(const f32x4*)&pcstg[row][col];
          size_t r = ((size_t)(tp + (row >> 3)) * BB + gb0 + (row & 7)) * 256;
          nt_store4(&out[O_PC + r + col], v);
        }
        if (hw == 0 && l < 48) {
          int s2 = l / 24, li = l % 24;
          f32x4 v = *(const f32x4*)&hdstg[s2][li * 4];
          nt_store4(&out[O_HD + ((size_t)(tp + s2) * BB + gb0) * 12 + li * 4], v);
        }
      }
      asm volatile("s_waitcnt lgkmcnt(0)" ::: "memory");
      __builtin_amdgcn_s_barrier();
      __builtin_amdgcn_sched_barrier(0);
    };

    auto heads_odd = [&](int t) {
      // ---- odd: compute pc/hd pair(t-3,t-2) -> pcstg/hdstg; store bo ----
      if (t >= 3 && t <= TT + 1) {
#pragma unroll
        for (int i = 0; i < 4; i++) {
          f32x4 pacc = bpcq[i];
          if (i < 2) {
#pragma unroll
            for (int s = 0; s < 4; s++) pacc = MFMA16(wpv[i][s], pb[s], pacc);
          } else {
#pragma unroll
            for (int s = 0; s < 4; s++) {
              bf16x8 fw = *(const bf16x8*)(wpcl + (size_t)((hw * 4 + i) * 4 + s) * 512 + l * 8);
              pacc = MFMA16(fw, pb[s], pacc);
            }
          }
          *(f32x4*)&pcstg[cl][(hw * 4 + i) * 16 + 4 * kg] = pacc;
        }
        if (hw == 0) {
          f32x4 hacc = bhdq;
#pragma unroll
          for (int s = 0; s < 4; s++) {
            bf16x8 fw = *(const bf16x8*)(whdl + (size_t)s * 512 + l * 8);
            hacc = MFMA16(fw, pb[s], hacc);
          }
          if (kg < 3) *(f32x4*)&hdstg[cl >> 3][(cl & 7) * 12 + 4 * kg] = hacc;
        }
        int tp = t - 3;
#pragma unroll
        for (int i = 0; i < 4; i++) {
          int f = (hw * 4 + i) * 256 + l * 4;     // one full row of bostg
          int row = f >> 8, col = f & 255;
          f32x4 v = *(const f32x4*)&bostg[row][col];
          size_t r = ((size_t)(tp + (row >> 3)) * BB + gb0 + (row & 7)) * 256;
          nt_store4(&out[O_BO + r + col], v);
        }
      }
      asm volatile("s_waitcnt lgkmcnt(0)" ::: "memory");
      __builtin_amdgcn_s_barrier();
      __builtin_amdgcn_sched_barrier(0);
    };

    for (int tb = 0; tb < 104; tb += 2) {
      heads_even(tb);
      heads_odd(tb + 1);
    }
  }
}

// ---------------------------------------------------------------------------
extern "C" void kernel_launch(void* const* d_in, const int* in_sizes, int n_in,
                              void* d_out, int out_size, void* d_ws, size_t ws_size,
                              hipStream_t stream) {
  const float* x   = (const float*)d_in[0];
  const float* ini = (const float*)d_in[1];
  const float* W   = (const float*)d_in[2];
  const float* U   = (const float*)d_in[3];
  const float* b   = (const float*)d_in[4];
  const float* Wh  = (const float*)d_in[5];
  const float* bh  = (const float*)d_in[6];
  const float* Wc  = (const float*)d_in[7];
  const float* bc  = (const float*)d_in[8];
  const float* Wb  = (const float*)d_in[9];
  const float* Wpc = (const float*)d_in[10];
  const float* bpc = (const float*)d_in[11];
  const float* Whd = (const float*)d_in[12];
  const float* bhd = (const float*)d_in[13];
  float* out = (float*)d_out;
  bf16_t* ws = (bf16_t*)d_ws;   // 149504 bf16 = 292 KB

  hipLaunchKernelGGL(prep_kernel, dim3(124), dim3(256), 0, stream, U, W, b, Wb, Wpc, Whd, ws);
  hipLaunchKernelGGL(lstm_fused, dim3(256), dim3(768), 0, stream,
                     x, ini, Wh, bh, Wc, bc, bpc, bhd, ws, out);
}

// Round 7
// 163.394 us; speedup vs baseline: 8.1743x; 1.0032x over previous
//
#include <hip/hip_runtime.h>

// ---------------------------------------------------------------------------
// Round 22: t-loop unroll x4 (was x2 in r21, which gave -5.9 µs confirming
// the in-flight-store/Little's-law theory). 4 textual window copies -> 4
// disjoint store-temp VGPR sets -> vmcnt reuse distance 4 windows (~24 MB
// in flight device-wide). LDS rings unchanged (store data is consumed from
// LDS into regs in the same window; only VGPR reuse distance matters).
// Everything else identical to r21 (fused, nt stores, setprio gates
// critical section, h/c stores on gate waves, fused pc/hd weights).
// MFMA 16x16x32 bf16 (m89): C/D: col=l&15 (batch), row=4*(l>>4)+j (feature).
// ---------------------------------------------------------------------------

typedef __bf16 bf16_t;
typedef __bf16 bf16x4 __attribute__((ext_vector_type(4)));
typedef __bf16 bf16x8 __attribute__((ext_vector_type(8)));
typedef float  f32x4  __attribute__((ext_vector_type(4)));

static_assert(sizeof(bf16x8) == 16, "bf16x8 must be 16B");

#define MFMA16(a, b, c) __builtin_amdgcn_mfma_f32_16x16x32_bf16((a), (b), (c), 0, 0, 0)

constexpr int TT = 100, BB = 2048;
constexpr long O_HD = 0;
constexpr long O_PC = O_HD + (long)TT * BB * 12;    // 2,457,600
constexpr long O_BO = O_PC + (long)TT * BB * 256;   // 54,886,400
constexpr long O_H  = O_BO + (long)TT * BB * 256;   // 107,315,200
constexpr long O_C  = O_H  + (long)TT * BB * 128;   // 133,529,600

// d_ws bf16 frag layout (A-operand order: entry = M[k][out_feature]):
constexpr int WS_U   = 0;        // 32 tiles x 5 s x 512 = 81920 (k128-130=W, k131=b)
constexpr int WS_WB  = 81920;    // 16 tiles x 4 s x 512 = 32768
constexpr int WS_WPF = 114688;   // fused Wb@Wpc: 16 tiles x 4 s x 512 = 32768
constexpr int WS_WHF = 147456;   // fused Wb@Whd: 1 tile x 4 s x 512 = 2048

__device__ __forceinline__ float fast_sigmoid(float x) {
  return __builtin_amdgcn_rcpf(1.0f + __builtin_amdgcn_exp2f(-1.442695040888963f * x));
}
__device__ __forceinline__ float fast_tanh(float x) {
  float e = __builtin_amdgcn_exp2f(2.885390081777927f * x);  // exp(2x)
  return 1.0f - 2.0f * __builtin_amdgcn_rcpf(e + 1.0f);
}

__device__ __forceinline__ void nt_store4(float* p, f32x4 v) {
  __builtin_nontemporal_store(v, (f32x4*)p);
}

// ---------------------------------------------------------------------------
// prep v2: blocks 0-39 U-aug repack; 40-55 Wb repack; 56-119 Wb@Wpc fusion
// (one (tile,s) combo per block, Wpc cols LDS-tiled, Wb rows broadcast);
// 120-123 Wb@Whd fusion.
// ---------------------------------------------------------------------------
__global__ void prep_kernel(const float* __restrict__ U, const float* __restrict__ W,
                            const float* __restrict__ b_, const float* __restrict__ Wb,
                            const float* __restrict__ Wpc, const float* __restrict__ Whd,
                            bf16_t* __restrict__ ws) {
  const int blk = blockIdx.x, tid = threadIdx.x;
  if (blk < 40) {                        // U augmented: 32 tiles x 5 K-slices
    int g = blk * 256 + tid;
    int tile = g / 320, rem = g % 320, s = rem >> 6, l = rem & 63;
    int cl = l & 15, kg = l >> 4, fb = tile * 16;
    bf16x8 v;
#pragma unroll
    for (int j = 0; j < 8; j++) {
      int k = 32 * s + 8 * kg + j;
      float e = 0.0f;
      if (k < 128) e = U[(size_t)k * 512 + fb + cl];
      else if (k < 131) e = W[(size_t)(k - 128) * 512 + fb + cl];
      else if (k == 131) e = b_[fb + cl];
      v[j] = (bf16_t)e;
    }
    *(bf16x8*)(ws + WS_U + (size_t)g * 8) = v;
  } else if (blk < 56) {                 // Wb^T frags: 16 tiles x 4 s
    int gg = (blk - 40) * 256 + tid;
    int tile = gg >> 8, s = (gg >> 6) & 3, l = gg & 63;
    int cl = l & 15, kg = l >> 4;
    bf16x8 v;
#pragma unroll
    for (int j = 0; j < 8; j++)
      v[j] = (bf16_t)Wb[(size_t)(32 * s + 8 * kg + j) * 256 + tile * 16 + cl];
    *(bf16x8*)(ws + WS_WB + (size_t)gg * 8) = v;
  } else if (blk < 120) {                // fused (Wb@Wpc)^T: one (tile,s)/block
    __shared__ float wpcol[256][17];
    int c = blk - 56, tile = c >> 2, s = c & 3;
    for (int i = tid; i < 4096; i += 256)
      wpcol[i >> 4][i & 15] = Wpc[(size_t)(i >> 4) * 256 + tile * 16 + (i & 15)];
    __syncthreads();
    int l = tid & 63, jp = tid >> 6;     // jp in 0..3 -> j = 2jp, 2jp+1
    int cl = l & 15, kg = l >> 4;
    const float* wb0 = Wb + (size_t)(32 * s + 8 * kg + 2 * jp) * 256;
    const float* wb1 = wb0 + 256;
    float d0 = 0.f, d1 = 0.f;
#pragma unroll 8
    for (int n = 0; n < 256; n++) {
      float wv = wpcol[n][cl];
      d0 += wb0[n] * wv;
      d1 += wb1[n] * wv;
    }
    bf16_t* dst = ws + WS_WPF + ((size_t)(tile * 4 + s) * 64 + l) * 8 + 2 * jp;
    dst[0] = (bf16_t)d0;
    dst[1] = (bf16_t)d1;
  } else {                               // fused (Wb@Whd)^T: one s/block (4)
    __shared__ float wpcol[256][17];
    int s = blk - 120;
    for (int i = tid; i < 4096; i += 256) {
      int n = i >> 4, p = i & 15;
      wpcol[n][p] = (p < 12) ? Whd[(size_t)n * 12 + p] : 0.0f;
    }
    __syncthreads();
    int l = tid & 63, jp = tid >> 6;
    int cl = l & 15, kg = l >> 4;
    const float* wb0 = Wb + (size_t)(32 * s + 8 * kg + 2 * jp) * 256;
    const float* wb1 = wb0 + 256;
    float d0 = 0.f, d1 = 0.f;
#pragma unroll 8
    for (int n = 0; n < 256; n++) {
      float wv = wpcol[n][cl];
      d0 += wb0[n] * wv;
      d1 += wb1[n] * wv;
    }
    bf16_t* dst = ws + WS_WHF + ((size_t)s * 64 + l) * 8 + 2 * jp;
    dst[0] = (bf16_t)d0;
    dst[1] = (bf16_t)d1;
  }
}

// ---------------------------------------------------------------------------
__global__ __launch_bounds__(768, 3) void lstm_fused(
    const float* __restrict__ x, const float* __restrict__ ini,
    const float* __restrict__ Wh, const float* __restrict__ bh,
    const float* __restrict__ Wc, const float* __restrict__ bc,
    const float* __restrict__ bpc, const float* __restrict__ bhd,
    const bf16_t* __restrict__ ws, float* __restrict__ out) {
  __shared__ bf16_t hl[2][16][168];     // h(0:128)|x(128:131)|0; rows 8-15 zero
  __shared__ bf16_t hp[2][16][136];     // pair buf: rows 0-7=h(2k), 8-15=h(2k+1)
  __shared__ bf16_t wpcl[32768];        // fused pc weight frags, 64 KB
  __shared__ bf16_t whdl[2048];         // fused hd weight frags, 4 KB
  __shared__ bf16_t xbl[TT][8][4];      // {x0,x1,x2,1.0} per (t,row), 6.25 KB
  __shared__ float  il[8][268];
  __shared__ float  cstg[2][8][132];    // fp32 c staging (dbuf), 8.25 KB
  __shared__ float  bostg[16][260];     // fp32 bo pair staging, 16.25 KB
  __shared__ float  pcstg[16][260];     // fp32 pc pair staging, 16.25 KB
  __shared__ float  hdstg[2][100];      // fp32 hd pair staging, 0.8 KB

  const int tid = threadIdx.x;
  const int w   = tid >> 6;             // 0..11
  const int l   = tid & 63;
  const int cl  = l & 15;
  const int kg  = l >> 4;
  const int gb0 = blockIdx.x * 8;

  // ---- cooperative LDS init (all 12 waves) ----
  for (int i = tid; i < 2 * 16 * 168; i += 768) ((bf16_t*)hl)[i] = (bf16_t)0.f;
  for (int i = tid; i < TT * 8; i += 768) {
    int t = i >> 3, r = i & 7;
    const float* xp = x + ((size_t)t * BB + gb0 + r) * 3;
    bf16x4 v = {(bf16_t)xp[0], (bf16_t)xp[1], (bf16_t)xp[2], (bf16_t)1.0f};
    *(bf16x4*)&xbl[t][r][0] = v;
  }
  for (int i = tid; i < 8 * 268; i += 768) {
    int r = i / 268, k = i - r * 268;
    il[r][k] = ini[(size_t)(gb0 + r) * 268 + k];
  }
  for (int c = tid; c < 4096; c += 768)
    *(bf16x8*)(wpcl + (size_t)c * 8) = *(const bf16x8*)(ws + WS_WPF + (size_t)c * 8);
  if (tid < 256)
    *(bf16x8*)(whdl + (size_t)tid * 8) = *(const bf16x8*)(ws + WS_WHF + (size_t)tid * 8);
  __syncthreads();

  if (w < 8) {
    // ================= GATES waves (recurrence critical path) =================
    const int fb4 = w * 16 + 4 * kg;    // 4 consecutive h-features owned

    // h/c store assignment: even wave -> h quarter, odd wave -> c quarter
    const int q    = w >> 1;            // quarter 0..3
    const int sf   = q * 256 + l * 4;   // flat float index in 8x128 region
    const int srow = sf >> 7;           // 2q or 2q+1
    const int scol = sf & 127;
    float* sptr = out + ((w & 1) ? O_C : O_H) + (size_t)gb0 * 128 + sf;  // tm=0

    bf16x8 uf[4][5];
#pragma unroll
    for (int n = 0; n < 4; n++)
#pragma unroll
      for (int s = 0; s < 5; s++)
        uf[n][s] = *(const bf16x8*)(ws + WS_U + (size_t)((n * 8 + w) * 5 + s) * 512 + l * 8);

    // ---- h0/c0 = init @ Wh/Wc + bh/bc ----
    f32x4 cst;
    {
      f32x4 ha = *(const f32x4*)&bh[fb4];
      f32x4 ca = *(const f32x4*)&bc[fb4];
      for (int k = 0; k < 268; k++) {
        float iv = il[cl & 7][k];
        ha += iv * *(const f32x4*)&Wh[(size_t)k * 128 + fb4];
        ca += iv * *(const f32x4*)&Wc[(size_t)k * 128 + fb4];
      }
      cst = ca;
      if (cl < 8) {
        bf16x4 hv = {(bf16_t)ha[0], (bf16_t)ha[1], (bf16_t)ha[2], (bf16_t)ha[3]};
        *(bf16x4*)&hl[0][cl][fb4] = hv;
      }
    }
    if (tid < 8) *(bf16x4*)&hl[0][tid][128] = *(const bf16x4*)&xbl[0][tid][0];
    asm volatile("s_waitcnt lgkmcnt(0)" ::: "memory");
    __builtin_amdgcn_s_barrier();

    auto gate_window = [&](int t) {
      // ---- store h(t-1) or c(t-1): one 1KB burst per wave ----
      if (t >= 1 && t <= TT) {
        int tm = t - 1;
        if (w & 1) {
          f32x4 vc = *(const f32x4*)&cstg[tm & 1][srow][scol];
          nt_store4(sptr, vc);
        } else {
          bf16x4 hb = *(const bf16x4*)&hp[(tm >> 1) & 1][(tm & 1) * 8 + srow][scol];
          f32x4 vh = {(float)hb[0], (float)hb[1], (float)hb[2], (float)hb[3]};
          nt_store4(sptr, vh);
        }
        sptr += (size_t)BB * 128;
      }
      if (t < TT) {
        bf16x8 hfrag[5];
#pragma unroll
        for (int s = 0; s < 5; s++) hfrag[s] = *(const bf16x8*)&hl[t & 1][cl][32 * s + 8 * kg];

        // critical section: boost wave priority through MFMA + activations
        __builtin_amdgcn_s_setprio(1);

        // split accumulator chains: depth 3 + depth 2, then add
        f32x4 acc[4], acc2[4];
#pragma unroll
        for (int n = 0; n < 4; n++) {
          acc[n]  = (f32x4){0.f, 0.f, 0.f, 0.f};
          acc2[n] = (f32x4){0.f, 0.f, 0.f, 0.f};
        }
#pragma unroll
        for (int s = 0; s < 3; s++)
#pragma unroll
          for (int n = 0; n < 4; n++) acc[n] = MFMA16(uf[n][s], hfrag[s], acc[n]);
#pragma unroll
        for (int s = 3; s < 5; s++)
#pragma unroll
          for (int n = 0; n < 4; n++) acc2[n] = MFMA16(uf[n][s], hfrag[s], acc2[n]);
#pragma unroll
        for (int n = 0; n < 4; n++) acc[n] += acc2[n];

        f32x4 hv4;
#pragma unroll
        for (int j = 0; j < 4; j++) {
          float iv = fast_sigmoid(acc[0][j]);
          float fv = fast_sigmoid(acc[1][j]);
          float gv = fast_tanh(acc[2][j]);
          float ov = fast_sigmoid(acc[3][j]);
          float cv = fv * cst[j] + iv * gv;
          cst[j] = cv;
          hv4[j] = ov * fast_tanh(cv);
        }
        if (cl < 8) {
          bf16x4 hb = {(bf16_t)hv4[0], (bf16_t)hv4[1], (bf16_t)hv4[2], (bf16_t)hv4[3]};
          *(bf16x4*)&hl[(t + 1) & 1][cl][fb4] = hb;
          *(bf16x4*)&hp[(t >> 1) & 1][(t & 1) * 8 + cl][fb4] = hb;
          *(f32x4*)&cstg[t & 1][cl][fb4] = cst;
        }
        __builtin_amdgcn_s_setprio(0);
        if (tid < 8 && t + 1 < TT)
          *(bf16x4*)&hl[(t + 1) & 1][tid][128] = *(const bf16x4*)&xbl[t + 1][tid][0];
      }
      asm volatile("s_waitcnt lgkmcnt(0)" ::: "memory");
      __builtin_amdgcn_s_barrier();
      __builtin_amdgcn_sched_barrier(0);
    };

    // unroll x4: 4 disjoint store-temp VGPR sets -> 4-window vmcnt reuse distance
    for (int tb = 0; tb < 104; tb += 4) {
      gate_window(tb);
      gate_window(tb + 1);
      gate_window(tb + 2);
      gate_window(tb + 3);
    }
  } else {
    // ============ HEADS waves (bo/pc/hd MFMA + bo/pc/hd stores) ============
    const int hw = w - 8;               // 0..3

    bf16x8 wbv[4][4], wpv[2][4];
#pragma unroll
    for (int i = 0; i < 4; i++)
#pragma unroll
      for (int s = 0; s < 4; s++)
        wbv[i][s] = *(const bf16x8*)(ws + WS_WB + (size_t)((hw * 4 + i) * 4 + s) * 512 + l * 8);
#pragma unroll
    for (int i = 0; i < 2; i++)
#pragma unroll
      for (int s = 0; s < 4; s++)
        wpv[i][s] = *(const bf16x8*)(ws + WS_WPF + (size_t)((hw * 4 + i) * 4 + s) * 512 + l * 8);
    f32x4 bpcq[4];
#pragma unroll
    for (int i = 0; i < 4; i++) bpcq[i] = *(const f32x4*)&bpc[(hw * 4 + i) * 16 + 4 * kg];
    f32x4 bhdq = (kg < 3) ? *(const f32x4*)&bhd[4 * kg] : (f32x4){0.f, 0.f, 0.f, 0.f};

    asm volatile("s_waitcnt lgkmcnt(0)" ::: "memory");
    __builtin_amdgcn_s_barrier();

    bf16x8 pb[4];                        // pair tile frags, live even->odd window

    auto heads_even = [&](int t) {
      // ---- even: compute bo pair(t-2,t-1) -> bostg ----
      if (t >= 2 && t <= TT) {
        int slot = ((t - 2) >> 1) & 1;
#pragma unroll
        for (int s = 0; s < 4; s++) pb[s] = *(const bf16x8*)&hp[slot][cl][32 * s + 8 * kg];
#pragma unroll
        for (int i = 0; i < 4; i++) {
          f32x4 bacc = {0.f, 0.f, 0.f, 0.f};
#pragma unroll
          for (int s = 0; s < 4; s++) bacc = MFMA16(wbv[i][s], pb[s], bacc);
          *(f32x4*)&bostg[cl][(hw * 4 + i) * 16 + 4 * kg] = bacc;
        }
      }
      // ---- even: store pc/hd pair(t-4,t-3) ----
      if (t >= 4) {
        int tp = t - 4;
#pragma unroll
        for (int i = 0; i < 4; i++) {
          int f = (hw * 4 + i) * 256 + l * 4;     // one full row of pcstg
          int row = f >> 8, col = f & 255;
          f32x4 v = *(const f32x4*)&pcstg[row][col];
          size_t r = ((size_t)(tp + (row >> 3)) * BB + gb0 + (row & 7)) * 256;
          nt_store4(&out[O_PC + r + col], v);
        }
        if (hw == 0 && l < 48) {
          int s2 = l / 24, li = l % 24;
          f32x4 v = *(const f32x4*)&hdstg[s2][li * 4];
          nt_store4(&out[O_HD + ((size_t)(tp + s2) * BB + gb0) * 12 + li * 4], v);
        }
      }
      asm volatile("s_waitcnt lgkmcnt(0)" ::: "memory");
      __builtin_amdgcn_s_barrier();
      __builtin_amdgcn_sched_barrier(0);
    };

    auto heads_odd = [&](int t) {
      // ---- odd: compute pc/hd pair(t-3,t-2) -> pcstg/hdstg; store bo ----
      if (t >= 3 && t <= TT + 1) {
#pragma unroll
        for (int i = 0; i < 4; i++) {
          f32x4 pacc = bpcq[i];
          if (i < 2) {
#pragma unroll
            for (int s = 0; s < 4; s++) pacc = MFMA16(wpv[i][s], pb[s], pacc);
          } else {
#pragma unroll
            for (int s = 0; s < 4; s++) {
              bf16x8 fw = *(const bf16x8*)(wpcl + (size_t)((hw * 4 + i) * 4 + s) * 512 + l * 8);
              pacc = MFMA16(fw, pb[s], pacc);
            }
          }
          *(f32x4*)&pcstg[cl][(hw * 4 + i) * 16 + 4 * kg] = pacc;
        }
        if (hw == 0) {
          f32x4 hacc = bhdq;
#pragma unroll
          for (int s = 0; s < 4; s++) {
            bf16x8 fw = *(const bf16x8*)(whdl + (size_t)s * 512 + l * 8);
            hacc = MFMA16(fw, pb[s], hacc);
          }
          if (kg < 3) *(f32x4*)&hdstg[cl >> 3][(cl & 7) * 12 + 4 * kg] = hacc;
        }
        int tp = t - 3;
#pragma unroll
        for (int i = 0; i < 4; i++) {
          int f = (hw * 4 + i) * 256 + l * 4;     // one full row of bostg
          int row = f >> 8, col = f & 255;
          f32x4 v = *(const f32x4*)&bostg[row][col];
          size_t r = ((size_t)(tp + (row >> 3)) * BB + gb0 + (row & 7)) * 256;
          nt_store4(&out[O_BO + r + col], v);
        }
      }
      asm volatile("s_waitcnt lgkmcnt(0)" ::: "memory");
      __builtin_amdgcn_s_barrier();
      __builtin_amdgcn_sched_barrier(0);
    };

    for (int tb = 0; tb < 104; tb += 4) {
      heads_even(tb);
      heads_odd(tb + 1);
      heads_even(tb + 2);
      heads_odd(tb + 3);
    }
  }
}

// ---------------------------------------------------------------------------
extern "C" void kernel_launch(void* const* d_in, const int* in_sizes, int n_in,
                              void* d_out, int out_size, void* d_ws, size_t ws_size,
                              hipStream_t stream) {
  const float* x   = (const float*)d_in[0];
  const float* ini = (const float*)d_in[1];
  const float* W   = (const float*)d_in[2];
  const float* U   = (const float*)d_in[3];
  const float* b   = (const float*)d_in[4];
  const float* Wh  = (const float*)d_in[5];
  const float* bh  = (const float*)d_in[6];
  const float* Wc  = (const float*)d_in[7];
  const float* bc  = (const float*)d_in[8];
  const float* Wb  = (const float*)d_in[9];
  const float* Wpc = (const float*)d_in[10];
  const float* bpc = (const float*)d_in[11];
  const float* Whd = (const float*)d_in[12];
  const float* bhd = (const float*)d_in[13];
  float* out = (float*)d_out;
  bf16_t* ws = (bf16_t*)d_ws;   // 149504 bf16 = 292 KB

  hipLaunchKernelGGL(prep_kernel, dim3(124), dim3(256), 0, stream, U, W, b, Wb, Wpc, Whd, ws);
  hipLaunchKernelGGL(lstm_fused, dim3(256), dim3(768), 0, stream,
                     x, ini, Wh, bh, Wc, bc, bpc, bhd, ws, out);
}

// Round 8
// 162.475 us; speedup vs baseline: 8.2206x; 1.0057x over previous
//
#include <hip/hip_runtime.h>

// ---------------------------------------------------------------------------
// Round 23: XCD-aware batch-chunk swizzle (T1 adapted to write streams).
// Default dispatch puts consecutive blockIdx (= adjacent batch rows =
// adjacent output addresses) on DIFFERENT XCDs -> each XCD's TCC sees
// 4-8KB chunks at 64KB stride in every region -> poor write-combining /
// HBM row locality. Swizzle: chunk = (bid%8)*32 + bid/8 (bijective, 256
// blocks = 8 XCD x 32) -> each XCD owns a contiguous 256-batch-row chunk;
// per-window per-region write-back per XCD becomes one ~128KB contiguous
// run. Single-line change vs r22 (gb0 computation). Everything else
// identical: unroll x4, nt stores, setprio, fused weights, h/c on gates.
// MFMA 16x16x32 bf16 (m89): C/D: col=l&15 (batch), row=4*(l>>4)+j (feature).
// ---------------------------------------------------------------------------

typedef __bf16 bf16_t;
typedef __bf16 bf16x4 __attribute__((ext_vector_type(4)));
typedef __bf16 bf16x8 __attribute__((ext_vector_type(8)));
typedef float  f32x4  __attribute__((ext_vector_type(4)));

static_assert(sizeof(bf16x8) == 16, "bf16x8 must be 16B");

#define MFMA16(a, b, c) __builtin_amdgcn_mfma_f32_16x16x32_bf16((a), (b), (c), 0, 0, 0)

constexpr int TT = 100, BB = 2048;
constexpr long O_HD = 0;
constexpr long O_PC = O_HD + (long)TT * BB * 12;    // 2,457,600
constexpr long O_BO = O_PC + (long)TT * BB * 256;   // 54,886,400
constexpr long O_H  = O_BO + (long)TT * BB * 256;   // 107,315,200
constexpr long O_C  = O_H  + (long)TT * BB * 128;   // 133,529,600

// d_ws bf16 frag layout (A-operand order: entry = M[k][out_feature]):
constexpr int WS_U   = 0;        // 32 tiles x 5 s x 512 = 81920 (k128-130=W, k131=b)
constexpr int WS_WB  = 81920;    // 16 tiles x 4 s x 512 = 32768
constexpr int WS_WPF = 114688;   // fused Wb@Wpc: 16 tiles x 4 s x 512 = 32768
constexpr int WS_WHF = 147456;   // fused Wb@Whd: 1 tile x 4 s x 512 = 2048

__device__ __forceinline__ float fast_sigmoid(float x) {
  return __builtin_amdgcn_rcpf(1.0f + __builtin_amdgcn_exp2f(-1.442695040888963f * x));
}
__device__ __forceinline__ float fast_tanh(float x) {
  float e = __builtin_amdgcn_exp2f(2.885390081777927f * x);  // exp(2x)
  return 1.0f - 2.0f * __builtin_amdgcn_rcpf(e + 1.0f);
}

__device__ __forceinline__ void nt_store4(float* p, f32x4 v) {
  __builtin_nontemporal_store(v, (f32x4*)p);
}

// ---------------------------------------------------------------------------
// prep v2: blocks 0-39 U-aug repack; 40-55 Wb repack; 56-119 Wb@Wpc fusion
// (one (tile,s) combo per block, Wpc cols LDS-tiled, Wb rows broadcast);
// 120-123 Wb@Whd fusion.
// ---------------------------------------------------------------------------
__global__ void prep_kernel(const float* __restrict__ U, const float* __restrict__ W,
                            const float* __restrict__ b_, const float* __restrict__ Wb,
                            const float* __restrict__ Wpc, const float* __restrict__ Whd,
                            bf16_t* __restrict__ ws) {
  const int blk = blockIdx.x, tid = threadIdx.x;
  if (blk < 40) {                        // U augmented: 32 tiles x 5 K-slices
    int g = blk * 256 + tid;
    int tile = g / 320, rem = g % 320, s = rem >> 6, l = rem & 63;
    int cl = l & 15, kg = l >> 4, fb = tile * 16;
    bf16x8 v;
#pragma unroll
    for (int j = 0; j < 8; j++) {
      int k = 32 * s + 8 * kg + j;
      float e = 0.0f;
      if (k < 128) e = U[(size_t)k * 512 + fb + cl];
      else if (k < 131) e = W[(size_t)(k - 128) * 512 + fb + cl];
      else if (k == 131) e = b_[fb + cl];
      v[j] = (bf16_t)e;
    }
    *(bf16x8*)(ws + WS_U + (size_t)g * 8) = v;
  } else if (blk < 56) {                 // Wb^T frags: 16 tiles x 4 s
    int gg = (blk - 40) * 256 + tid;
    int tile = gg >> 8, s = (gg >> 6) & 3, l = gg & 63;
    int cl = l & 15, kg = l >> 4;
    bf16x8 v;
#pragma unroll
    for (int j = 0; j < 8; j++)
      v[j] = (bf16_t)Wb[(size_t)(32 * s + 8 * kg + j) * 256 + tile * 16 + cl];
    *(bf16x8*)(ws + WS_WB + (size_t)gg * 8) = v;
  } else if (blk < 120) {                // fused (Wb@Wpc)^T: one (tile,s)/block
    __shared__ float wpcol[256][17];
    int c = blk - 56, tile = c >> 2, s = c & 3;
    for (int i = tid; i < 4096; i += 256)
      wpcol[i >> 4][i & 15] = Wpc[(size_t)(i >> 4) * 256 + tile * 16 + (i & 15)];
    __syncthreads();
    int l = tid & 63, jp = tid >> 6;     // jp in 0..3 -> j = 2jp, 2jp+1
    int cl = l & 15, kg = l >> 4;
    const float* wb0 = Wb + (size_t)(32 * s + 8 * kg + 2 * jp) * 256;
    const float* wb1 = wb0 + 256;
    float d0 = 0.f, d1 = 0.f;
#pragma unroll 8
    for (int n = 0; n < 256; n++) {
      float wv = wpcol[n][cl];
      d0 += wb0[n] * wv;
      d1 += wb1[n] * wv;
    }
    bf16_t* dst = ws + WS_WPF + ((size_t)(tile * 4 + s) * 64 + l) * 8 + 2 * jp;
    dst[0] = (bf16_t)d0;
    dst[1] = (bf16_t)d1;
  } else {                               // fused (Wb@Whd)^T: one s/block (4)
    __shared__ float wpcol[256][17];
    int s = blk - 120;
    for (int i = tid; i < 4096; i += 256) {
      int n = i >> 4, p = i & 15;
      wpcol[n][p] = (p < 12) ? Whd[(size_t)n * 12 + p] : 0.0f;
    }
    __syncthreads();
    int l = tid & 63, jp = tid >> 6;
    int cl = l & 15, kg = l >> 4;
    const float* wb0 = Wb + (size_t)(32 * s + 8 * kg + 2 * jp) * 256;
    const float* wb1 = wb0 + 256;
    float d0 = 0.f, d1 = 0.f;
#pragma unroll 8
    for (int n = 0; n < 256; n++) {
      float wv = wpcol[n][cl];
      d0 += wb0[n] * wv;
      d1 += wb1[n] * wv;
    }
    bf16_t* dst = ws + WS_WHF + ((size_t)s * 64 + l) * 8 + 2 * jp;
    dst[0] = (bf16_t)d0;
    dst[1] = (bf16_t)d1;
  }
}

// ---------------------------------------------------------------------------
__global__ __launch_bounds__(768, 3) void lstm_fused(
    const float* __restrict__ x, const float* __restrict__ ini,
    const float* __restrict__ Wh, const float* __restrict__ bh,
    const float* __restrict__ Wc, const float* __restrict__ bc,
    const float* __restrict__ bpc, const float* __restrict__ bhd,
    const bf16_t* __restrict__ ws, float* __restrict__ out) {
  __shared__ bf16_t hl[2][16][168];     // h(0:128)|x(128:131)|0; rows 8-15 zero
  __shared__ bf16_t hp[2][16][136];     // pair buf: rows 0-7=h(2k), 8-15=h(2k+1)
  __shared__ bf16_t wpcl[32768];        // fused pc weight frags, 64 KB
  __shared__ bf16_t whdl[2048];         // fused hd weight frags, 4 KB
  __shared__ bf16_t xbl[TT][8][4];      // {x0,x1,x2,1.0} per (t,row), 6.25 KB
  __shared__ float  il[8][268];
  __shared__ float  cstg[2][8][132];    // fp32 c staging (dbuf), 8.25 KB
  __shared__ float  bostg[16][260];     // fp32 bo pair staging, 16.25 KB
  __shared__ float  pcstg[16][260];     // fp32 pc pair staging, 16.25 KB
  __shared__ float  hdstg[2][100];      // fp32 hd pair staging, 0.8 KB

  const int tid = threadIdx.x;
  const int w   = tid >> 6;             // 0..11
  const int l   = tid & 63;
  const int cl  = l & 15;
  const int kg  = l >> 4;
  // XCD-aware swizzle: block bid lands on XCD bid%8 (round-robin dispatch);
  // give XCD k the contiguous batch chunk k*256..k*256+255.
  const int gb0 = (((blockIdx.x & 7) * 32) + (blockIdx.x >> 3)) * 8;

  // ---- cooperative LDS init (all 12 waves) ----
  for (int i = tid; i < 2 * 16 * 168; i += 768) ((bf16_t*)hl)[i] = (bf16_t)0.f;
  for (int i = tid; i < TT * 8; i += 768) {
    int t = i >> 3, r = i & 7;
    const float* xp = x + ((size_t)t * BB + gb0 + r) * 3;
    bf16x4 v = {(bf16_t)xp[0], (bf16_t)xp[1], (bf16_t)xp[2], (bf16_t)1.0f};
    *(bf16x4*)&xbl[t][r][0] = v;
  }
  for (int i = tid; i < 8 * 268; i += 768) {
    int r = i / 268, k = i - r * 268;
    il[r][k] = ini[(size_t)(gb0 + r) * 268 + k];
  }
  for (int c = tid; c < 4096; c += 768)
    *(bf16x8*)(wpcl + (size_t)c * 8) = *(const bf16x8*)(ws + WS_WPF + (size_t)c * 8);
  if (tid < 256)
    *(bf16x8*)(whdl + (size_t)tid * 8) = *(const bf16x8*)(ws + WS_WHF + (size_t)tid * 8);
  __syncthreads();

  if (w < 8) {
    // ================= GATES waves (recurrence critical path) =================
    const int fb4 = w * 16 + 4 * kg;    // 4 consecutive h-features owned

    // h/c store assignment: even wave -> h quarter, odd wave -> c quarter
    const int q    = w >> 1;            // quarter 0..3
    const int sf   = q * 256 + l * 4;   // flat float index in 8x128 region
    const int srow = sf >> 7;           // 2q or 2q+1
    const int scol = sf & 127;
    float* sptr = out + ((w & 1) ? O_C : O_H) + (size_t)gb0 * 128 + sf;  // tm=0

    bf16x8 uf[4][5];
#pragma unroll
    for (int n = 0; n < 4; n++)
#pragma unroll
      for (int s = 0; s < 5; s++)
        uf[n][s] = *(const bf16x8*)(ws + WS_U + (size_t)((n * 8 + w) * 5 + s) * 512 + l * 8);

    // ---- h0/c0 = init @ Wh/Wc + bh/bc ----
    f32x4 cst;
    {
      f32x4 ha = *(const f32x4*)&bh[fb4];
      f32x4 ca = *(const f32x4*)&bc[fb4];
      for (int k = 0; k < 268; k++) {
        float iv = il[cl & 7][k];
        ha += iv * *(const f32x4*)&Wh[(size_t)k * 128 + fb4];
        ca += iv * *(const f32x4*)&Wc[(size_t)k * 128 + fb4];
      }
      cst = ca;
      if (cl < 8) {
        bf16x4 hv = {(bf16_t)ha[0], (bf16_t)ha[1], (bf16_t)ha[2], (bf16_t)ha[3]};
        *(bf16x4*)&hl[0][cl][fb4] = hv;
      }
    }
    if (tid < 8) *(bf16x4*)&hl[0][tid][128] = *(const bf16x4*)&xbl[0][tid][0];
    asm volatile("s_waitcnt lgkmcnt(0)" ::: "memory");
    __builtin_amdgcn_s_barrier();

    auto gate_window = [&](int t) {
      // ---- store h(t-1) or c(t-1): one 1KB burst per wave ----
      if (t >= 1 && t <= TT) {
        int tm = t - 1;
        if (w & 1) {
          f32x4 vc = *(const f32x4*)&cstg[tm & 1][srow][scol];
          nt_store4(sptr, vc);
        } else {
          bf16x4 hb = *(const bf16x4*)&hp[(tm >> 1) & 1][(tm & 1) * 8 + srow][scol];
          f32x4 vh = {(float)hb[0], (float)hb[1], (float)hb[2], (float)hb[3]};
          nt_store4(sptr, vh);
        }
        sptr += (size_t)BB * 128;
      }
      if (t < TT) {
        bf16x8 hfrag[5];
#pragma unroll
        for (int s = 0; s < 5; s++) hfrag[s] = *(const bf16x8*)&hl[t & 1][cl][32 * s + 8 * kg];

        // critical section: boost wave priority through MFMA + activations
        __builtin_amdgcn_s_setprio(1);

        // split accumulator chains: depth 3 + depth 2, then add
        f32x4 acc[4], acc2[4];
#pragma unroll
        for (int n = 0; n < 4; n++) {
          acc[n]  = (f32x4){0.f, 0.f, 0.f, 0.f};
          acc2[n] = (f32x4){0.f, 0.f, 0.f, 0.f};
        }
#pragma unroll
        for (int s = 0; s < 3; s++)
#pragma unroll
          for (int n = 0; n < 4; n++) acc[n] = MFMA16(uf[n][s], hfrag[s], acc[n]);
#pragma unroll
        for (int s = 3; s < 5; s++)
#pragma unroll
          for (int n = 0; n < 4; n++) acc2[n] = MFMA16(uf[n][s], hfrag[s], acc2[n]);
#pragma unroll
        for (int n = 0; n < 4; n++) acc[n] += acc2[n];

        f32x4 hv4;
#pragma unroll
        for (int j = 0; j < 4; j++) {
          float iv = fast_sigmoid(acc[0][j]);
          float fv = fast_sigmoid(acc[1][j]);
          float gv = fast_tanh(acc[2][j]);
          float ov = fast_sigmoid(acc[3][j]);
          float cv = fv * cst[j] + iv * gv;
          cst[j] = cv;
          hv4[j] = ov * fast_tanh(cv);
        }
        if (cl < 8) {
          bf16x4 hb = {(bf16_t)hv4[0], (bf16_t)hv4[1], (bf16_t)hv4[2], (bf16_t)hv4[3]};
          *(bf16x4*)&hl[(t + 1) & 1][cl][fb4] = hb;
          *(bf16x4*)&hp[(t >> 1) & 1][(t & 1) * 8 + cl][fb4] = hb;
          *(f32x4*)&cstg[t & 1][cl][fb4] = cst;
        }
        __builtin_amdgcn_s_setprio(0);
        if (tid < 8 && t + 1 < TT)
          *(bf16x4*)&hl[(t + 1) & 1][tid][128] = *(const bf16x4*)&xbl[t + 1][tid][0];
      }
      asm volatile("s_waitcnt lgkmcnt(0)" ::: "memory");
      __builtin_amdgcn_s_barrier();
      __builtin_amdgcn_sched_barrier(0);
    };

    // unroll x4: 4 disjoint store-temp VGPR sets -> 4-window vmcnt reuse distance
    for (int tb = 0; tb < 104; tb += 4) {
      gate_window(tb);
      gate_window(tb + 1);
      gate_window(tb + 2);
      gate_window(tb + 3);
    }
  } else {
    // ============ HEADS waves (bo/pc/hd MFMA + bo/pc/hd stores) ============
    const int hw = w - 8;               // 0..3

    bf16x8 wbv[4][4], wpv[2][4];
#pragma unroll
    for (int i = 0; i < 4; i++)
#pragma unroll
      for (int s = 0; s < 4; s++)
        wbv[i][s] = *(const bf16x8*)(ws + WS_WB + (size_t)((hw * 4 + i) * 4 + s) * 512 + l * 8);
#pragma unroll
    for (int i = 0; i < 2; i++)
#pragma unroll
      for (int s = 0; s < 4; s++)
        wpv[i][s] = *(const bf16x8*)(ws + WS_WPF + (size_t)((hw * 4 + i) * 4 + s) * 512 + l * 8);
    f32x4 bpcq[4];
#pragma unroll
    for (int i = 0; i < 4; i++) bpcq[i] = *(const f32x4*)&bpc[(hw * 4 + i) * 16 + 4 * kg];
    f32x4 bhdq = (kg < 3) ? *(const f32x4*)&bhd[4 * kg] : (f32x4){0.f, 0.f, 0.f, 0.f};

    asm volatile("s_waitcnt lgkmcnt(0)" ::: "memory");
    __builtin_amdgcn_s_barrier();

    bf16x8 pb[4];                        // pair tile frags, live even->odd window

    auto heads_even = [&](int t) {
      // ---- even: compute bo pair(t-2,t-1) -> bostg ----
      if (t >= 2 && t <= TT) {
        int slot = ((t - 2) >> 1) & 1;
#pragma unroll
        for (int s = 0; s < 4; s++) pb[s] = *(const bf16x8*)&hp[slot][cl][32 * s + 8 * kg];
#pragma unroll
        for (int i = 0; i < 4; i++) {
          f32x4 bacc = {0.f, 0.f, 0.f, 0.f};
#pragma unroll
          for (int s = 0; s < 4; s++) bacc = MFMA16(wbv[i][s], pb[s], bacc);
          *(f32x4*)&bostg[cl][(hw * 4 + i) * 16 + 4 * kg] = bacc;
        }
      }
      // ---- even: store pc/hd pair(t-4,t-3) ----
      if (t >= 4) {
        int tp = t - 4;
#pragma unroll
        for (int i = 0; i < 4; i++) {
          int f = (hw * 4 + i) * 256 + l * 4;     // one full row of pcstg
          int row = f >> 8, col = f & 255;
          f32x4 v = *(const f32x4*)&pcstg[row][col];
          size_t r = ((size_t)(tp + (row >> 3)) * BB + gb0 + (row & 7)) * 256;
          nt_store4(&out[O_PC + r + col], v);
        }
        if (hw == 0 && l < 48) {
          int s2 = l / 24, li = l % 24;
          f32x4 v = *(const f32x4*)&hdstg[s2][li * 4];
          nt_store4(&out[O_HD + ((size_t)(tp + s2) * BB + gb0) * 12 + li * 4], v);
        }
      }
      asm volatile("s_waitcnt lgkmcnt(0)" ::: "memory");
      __builtin_amdgcn_s_barrier();
      __builtin_amdgcn_sched_barrier(0);
    };

    auto heads_odd = [&](int t) {
      // ---- odd: compute pc/hd pair(t-3,t-2) -> pcstg/hdstg; store bo ----
      if (t >= 3 && t <= TT + 1) {
#pragma unroll
        for (int i = 0; i < 4; i++) {
          f32x4 pacc = bpcq[i];
          if (i < 2) {
#pragma unroll
            for (int s = 0; s < 4; s++) pacc = MFMA16(wpv[i][s], pb[s], pacc);
          } else {
#pragma unroll
            for (int s = 0; s < 4; s++) {
              bf16x8 fw = *(const bf16x8*)(wpcl + (size_t)((hw * 4 + i) * 4 + s) * 512 + l * 8);
              pacc = MFMA16(fw, pb[s], pacc);
            }
          }
          *(f32x4*)&pcstg[cl][(hw * 4 + i) * 16 + 4 * kg] = pacc;
        }
        if (hw == 0) {
          f32x4 hacc = bhdq;
#pragma unroll
          for (int s = 0; s < 4; s++) {
            bf16x8 fw = *(const bf16x8*)(whdl + (size_t)s * 512 + l * 8);
            hacc = MFMA16(fw, pb[s], hacc);
          }
          if (kg < 3) *(f32x4*)&hdstg[cl >> 3][(cl & 7) * 12 + 4 * kg] = hacc;
        }
        int tp = t - 3;
#pragma unroll
        for (int i = 0; i < 4; i++) {
          int f = (hw * 4 + i) * 256 + l * 4;     // one full row of bostg
          int row = f >> 8, col = f & 255;
          f32x4 v = *(const f32x4*)&bostg[row][col];
          size_t r = ((size_t)(tp + (row >> 3)) * BB + gb0 + (row & 7)) * 256;
          nt_store4(&out[O_BO + r + col], v);
        }
      }
      asm volatile("s_waitcnt lgkmcnt(0)" ::: "memory");
      __builtin_amdgcn_s_barrier();
      __builtin_amdgcn_sched_barrier(0);
    };

    for (int tb = 0; tb < 104; tb += 4) {
      heads_even(tb);
      heads_odd(tb + 1);
      heads_even(tb + 2);
      heads_odd(tb + 3);
    }
  }
}

// ---------------------------------------------------------------------------
extern "C" void kernel_launch(void* const* d_in, const int* in_sizes, int n_in,
                              void* d_out, int out_size, void* d_ws, size_t ws_size,
                              hipStream_t stream) {
  const float* x   = (const float*)d_in[0];
  const float* ini = (const float*)d_in[1];
  const float* W   = (const float*)d_in[2];
  const float* U   = (const float*)d_in[3];
  const float* b   = (const float*)d_in[4];
  const float* Wh  = (const float*)d_in[5];
  const float* bh  = (const float*)d_in[6];
  const float* Wc  = (const float*)d_in[7];
  const float* bc  = (const float*)d_in[8];
  const float* Wb  = (const float*)d_in[9];
  const float* Wpc = (const float*)d_in[10];
  const float* bpc = (const float*)d_in[11];
  const float* Whd = (const float*)d_in[12];
  const float* bhd = (const float*)d_in[13];
  float* out = (float*)d_out;
  bf16_t* ws = (bf16_t*)d_ws;   // 149504 bf16 = 292 KB

  hipLaunchKernelGGL(prep_kernel, dim3(124), dim3(256), 0, stream, U, W, b, Wb, Wpc, Whd, ws);
  hipLaunchKernelGGL(lstm_fused, dim3(256), dim3(768), 0, stream,
                     x, ini, Wh, bh, Wc, bc, bpc, bhd, ws, out);
}